// Round 2
// baseline (476.939 us; speedup 1.0000x reference)
//
#include <hip/hip_runtime.h>
#include <math.h>

#define BB 4
#define LL 1024
#define DD 256
#define NT (BB*LL)          // 4096 tokens
#define LN_EPS 1e-5f

// workspace layout (floats)
#define OFF_PQ   0
#define OFF_PK   (NT*DD)
#define OFF_V    (2*NT*DD)
#define OFF_Y    (3*NT*DD)      // also q staging before phi
#define OFF_LNY  (4*NT*DD)      // also k staging before phi
#define OFF_BETA (5*NT*DD)

// ---------------------------------------------------------------------------
// GEMM: C[t][j] = sum_d A[t][d] * W[j][d]  (+ bias[j])   A:[NT x DD], W:[DD x DD]
// BM=64, BN=64, BK=16, 256 threads, 4x4 micro-tile
// ---------------------------------------------------------------------------
__global__ __launch_bounds__(256)
void gemm_nt_kernel(const float* __restrict__ A, const float* __restrict__ W,
                    const float* __restrict__ bias, float* __restrict__ C)
{
    __shared__ float As[64][17];
    __shared__ float Bs[64][17];
    const int tid = threadIdx.x;
    const int t0 = blockIdx.x * 64;
    const int j0 = blockIdx.y * 64;
    const int ty = tid >> 4, tx = tid & 15;
    const int lr = tid >> 2, lc = (tid & 3) << 2;   // loader: row, col(4-wide)

    float acc[4][4];
    #pragma unroll
    for (int m = 0; m < 4; ++m)
        #pragma unroll
        for (int n = 0; n < 4; ++n) acc[m][n] = 0.f;

    for (int d0 = 0; d0 < DD; d0 += 16) {
        float4 av = *(const float4*)(A + (size_t)(t0 + lr) * DD + d0 + lc);
        float4 bv = *(const float4*)(W + (size_t)(j0 + lr) * DD + d0 + lc);
        As[lr][lc] = av.x; As[lr][lc+1] = av.y; As[lr][lc+2] = av.z; As[lr][lc+3] = av.w;
        Bs[lr][lc] = bv.x; Bs[lr][lc+1] = bv.y; Bs[lr][lc+2] = bv.z; Bs[lr][lc+3] = bv.w;
        __syncthreads();
        #pragma unroll
        for (int kk = 0; kk < 16; ++kk) {
            float a[4], b[4];
            #pragma unroll
            for (int m = 0; m < 4; ++m) a[m] = As[ty*4+m][kk];
            #pragma unroll
            for (int n = 0; n < 4; ++n) b[n] = Bs[tx*4+n][kk];
            #pragma unroll
            for (int m = 0; m < 4; ++m)
                #pragma unroll
                for (int n = 0; n < 4; ++n) acc[m][n] += a[m]*b[n];
        }
        __syncthreads();
    }

    #pragma unroll
    for (int m = 0; m < 4; ++m) {
        float4 o;
        o.x = acc[m][0]; o.y = acc[m][1]; o.z = acc[m][2]; o.w = acc[m][3];
        if (bias) {
            o.x += bias[j0 + tx*4 + 0];
            o.y += bias[j0 + tx*4 + 1];
            o.z += bias[j0 + tx*4 + 2];
            o.w += bias[j0 + tx*4 + 3];
        }
        *(float4*)(C + (size_t)(t0 + ty*4 + m) * DD + j0 + tx*4) = o;
    }
}

// ---------------------------------------------------------------------------
// phi kernel: per token t -> pq = LN(elu(q)+1), pk = LN(elu(k)+1),
//             beta[t] = sigmoid(x . beta_w + beta_b)
// one block of 256 threads per token
// ---------------------------------------------------------------------------
__global__ __launch_bounds__(256)
void phi_kernel(const float* __restrict__ q, const float* __restrict__ k,
                const float* __restrict__ x, const float* __restrict__ beta_w,
                const float* __restrict__ beta_b,
                const float* __restrict__ lnp_g, const float* __restrict__ lnp_b,
                float* __restrict__ pq, float* __restrict__ pk,
                float* __restrict__ betas)
{
    const int t = blockIdx.x;
    const int j = threadIdx.x;
    const size_t base = (size_t)t * DD;

    float qv = q[base + j], kv = k[base + j], xv = x[base + j];
    float eq = qv > 0.f ? qv + 1.f : expf(qv);
    float ek = kv > 0.f ? kv + 1.f : expf(kv);
    float bd = xv * beta_w[j];

    float s0 = eq, s1 = eq*eq, s2 = ek, s3 = ek*ek, s4 = bd;
    #pragma unroll
    for (int off = 32; off; off >>= 1) {
        s0 += __shfl_xor(s0, off);
        s1 += __shfl_xor(s1, off);
        s2 += __shfl_xor(s2, off);
        s3 += __shfl_xor(s3, off);
        s4 += __shfl_xor(s4, off);
    }
    __shared__ float red[4][5];
    const int lane = j & 63, w = j >> 6;
    if (lane == 0) { red[w][0]=s0; red[w][1]=s1; red[w][2]=s2; red[w][3]=s3; red[w][4]=s4; }
    __syncthreads();
    float T0 = red[0][0]+red[1][0]+red[2][0]+red[3][0];
    float T1 = red[0][1]+red[1][1]+red[2][1]+red[3][1];
    float T2 = red[0][2]+red[1][2]+red[2][2]+red[3][2];
    float T3 = red[0][3]+red[1][3]+red[2][3]+red[3][3];
    float T4 = red[0][4]+red[1][4]+red[2][4]+red[3][4];

    float mu_q = T0 * (1.f/DD);
    float var_q = T1 * (1.f/DD) - mu_q*mu_q;
    float rs_q = rsqrtf(var_q + LN_EPS);
    float mu_k = T2 * (1.f/DD);
    float var_k = T3 * (1.f/DD) - mu_k*mu_k;
    float rs_k = rsqrtf(var_k + LN_EPS);

    pq[base + j] = (eq - mu_q) * rs_q * lnp_g[j] + lnp_b[j];
    pk[base + j] = (ek - mu_k) * rs_k * lnp_g[j] + lnp_b[j];
    if (j == 0) betas[t] = 1.f / (1.f + expf(-(T4 + beta_b[0])));
}

// ---------------------------------------------------------------------------
// LN kernel: per token LN(y) with ln_g, ln_b
// ---------------------------------------------------------------------------
__global__ __launch_bounds__(256)
void ln_kernel(const float* __restrict__ y, const float* __restrict__ g,
               const float* __restrict__ b, float* __restrict__ out)
{
    const int t = blockIdx.x;
    const int j = threadIdx.x;
    const size_t base = (size_t)t * DD;
    float v = y[base + j];
    float s0 = v, s1 = v*v;
    #pragma unroll
    for (int off = 32; off; off >>= 1) {
        s0 += __shfl_xor(s0, off);
        s1 += __shfl_xor(s1, off);
    }
    __shared__ float red[4][2];
    const int lane = j & 63, w = j >> 6;
    if (lane == 0) { red[w][0]=s0; red[w][1]=s1; }
    __syncthreads();
    float T0 = red[0][0]+red[1][0]+red[2][0]+red[3][0];
    float T1 = red[0][1]+red[1][1]+red[2][1]+red[3][1];
    float mu = T0 * (1.f/DD);
    float var = T1 * (1.f/DD) - mu*mu;
    float rs = rsqrtf(var + LN_EPS);
    out[base + j] = (v - mu) * rs * g[j] + b[j];
}

// ---------------------------------------------------------------------------
// Fast-weight recurrence. One wave per (b, i): state w_i = W[b][i][:] as
// float4/lane. Per step: r = w.phi_q, vb = w.phi_k (64-lane butterfly),
// u = beta*(v_i - vb), w = df*w + u*phi_k. Next-step loads prefetched.
// grid 256 blocks x 256 threads = 1024 waves (1/SIMD over 256 CUs).
// ---------------------------------------------------------------------------
__global__ __launch_bounds__(256)
void recur_kernel(const float* __restrict__ pq, const float* __restrict__ pk,
                  const float* __restrict__ v, const float* __restrict__ betas,
                  const float* __restrict__ decay, float* __restrict__ y)
{
    const int gtid = blockIdx.x * 256 + threadIdx.x;
    const int wid = gtid >> 6;          // 0..1023
    const int lane = threadIdx.x & 63;
    const int b = wid >> 8;             // batch
    const int i = wid & 255;            // row of W
    const float df = 1.f / (1.f + expf(-decay[0]));

    const float* pqb = pq + (size_t)b * LL * DD;
    const float* pkb = pk + (size_t)b * LL * DD;
    const float* vb_ = v  + (size_t)b * LL * DD;
    const float* bb  = betas + (size_t)b * LL;
    float* yb = y + (size_t)b * LL * DD;

    const int col = lane * 4;
    float4 w = make_float4(0.f, 0.f, 0.f, 0.f);

    float4 q4 = *(const float4*)(pqb + col);
    float4 k4 = *(const float4*)(pkb + col);
    float vi = vb_[i];
    float bt = bb[0];

    for (int t = 0; t < LL; ++t) {
        const int tn = (t + 1 < LL) ? t + 1 : t;
        float4 nq = *(const float4*)(pqb + (size_t)tn * DD + col);
        float4 nk = *(const float4*)(pkb + (size_t)tn * DD + col);
        float nvi = vb_[(size_t)tn * DD + i];
        float nbt = bb[tn];

        float r  = w.x*q4.x + w.y*q4.y + w.z*q4.z + w.w*q4.w;
        float vr = w.x*k4.x + w.y*k4.y + w.z*k4.z + w.w*k4.w;
        #pragma unroll
        for (int off = 32; off; off >>= 1) {
            r  += __shfl_xor(r,  off);
            vr += __shfl_xor(vr, off);
        }
        float u = bt * (vi - vr);
        w.x = df*w.x + u*k4.x;
        w.y = df*w.y + u*k4.y;
        w.z = df*w.z + u*k4.z;
        w.w = df*w.w + u*k4.w;
        if (lane == 0) yb[(size_t)t * DD + i] = r;

        q4 = nq; k4 = nk; vi = nvi; bt = nbt;
    }
}

// ---------------------------------------------------------------------------
extern "C" void kernel_launch(void* const* d_in, const int* in_sizes, int n_in,
                              void* d_out, int out_size, void* d_ws, size_t ws_size,
                              hipStream_t stream)
{
    const float* x      = (const float*)d_in[0];
    const float* Wq     = (const float*)d_in[1];
    const float* Wk     = (const float*)d_in[2];
    const float* Wv     = (const float*)d_in[3];
    const float* beta_w = (const float*)d_in[4];
    const float* beta_b = (const float*)d_in[5];
    const float* decay  = (const float*)d_in[6];
    const float* Wo     = (const float*)d_in[7];
    const float* bo     = (const float*)d_in[8];
    const float* ln_g   = (const float*)d_in[9];
    const float* ln_b   = (const float*)d_in[10];
    const float* lnp_g  = (const float*)d_in[11];
    const float* lnp_b  = (const float*)d_in[12];

    float* ws = (float*)d_ws;
    float* q_st  = ws + OFF_Y;     // q staging (reused later for y)
    float* k_st  = ws + OFF_LNY;   // k staging (reused later for ln(y))
    float* v_st  = ws + OFF_V;
    float* pq    = ws + OFF_PQ;
    float* pk    = ws + OFF_PK;
    float* betas = ws + OFF_BETA;

    dim3 gemm_grid(NT/64, DD/64);

    // projections
    gemm_nt_kernel<<<gemm_grid, 256, 0, stream>>>(x, Wq, nullptr, q_st);
    gemm_nt_kernel<<<gemm_grid, 256, 0, stream>>>(x, Wk, nullptr, k_st);
    gemm_nt_kernel<<<gemm_grid, 256, 0, stream>>>(x, Wv, nullptr, v_st);

    // phi + beta
    phi_kernel<<<NT, 256, 0, stream>>>(q_st, k_st, x, beta_w, beta_b,
                                       lnp_g, lnp_b, pq, pk, betas);

    // sequential fast-weight recurrence (y overwrites q staging)
    recur_kernel<<<256, 256, 0, stream>>>(pq, pk, v_st, betas, decay, ws + OFF_Y);

    // final LN (overwrites k staging) + output projection
    ln_kernel<<<NT, 256, 0, stream>>>(ws + OFF_Y, ln_g, ln_b, ws + OFF_LNY);
    gemm_nt_kernel<<<gemm_grid, 256, 0, stream>>>(ws + OFF_LNY, Wo, bo, (float*)d_out);
}

// Round 4
// 274.352 us; speedup vs baseline: 1.7384x; 1.7384x over previous
//
#include <hip/hip_runtime.h>
#include <math.h>

#define BB 4
#define LL 1024
#define DD 256
#define NT (BB*LL)          // 4096 tokens
#define LN_EPS 1e-5f

// workspace layout (floats)
#define OFF_PQ   0
#define OFF_PK   (NT*DD)
#define OFF_V    (2*NT*DD)
#define OFF_Y    (3*NT*DD)      // also q staging before phi
#define OFF_LNY  (4*NT*DD)      // also k staging before phi
#define OFF_BETA (5*NT*DD)

// DPP-assisted add: x + dpp_move(x, ctrl); invalid source lanes contribute 0
// (bound_ctrl=true). row_shr chain accumulates into lane 15 of each 16-row;
// row_bcast15/31 cascade row sums; total lands in lane 63.
#define DPP_ADD(x, ctrl) ((x) + __uint_as_float(__builtin_amdgcn_update_dpp( \
        0u, __float_as_uint(x), (ctrl), 0xf, 0xf, true)))

// ---------------------------------------------------------------------------
// GEMM: C[t][j] = sum_d A[t][d] * W[j][d]  (+ bias[j])   A:[NT x DD], W:[DD x DD]
// BM=64, BN=64, BK=16, 256 threads, 4x4 micro-tile
// ---------------------------------------------------------------------------
__global__ __launch_bounds__(256)
void gemm_nt_kernel(const float* __restrict__ A, const float* __restrict__ W,
                    const float* __restrict__ bias, float* __restrict__ C)
{
    __shared__ float As[64][17];
    __shared__ float Bs[64][17];
    const int tid = threadIdx.x;
    const int t0 = blockIdx.x * 64;
    const int j0 = blockIdx.y * 64;
    const int ty = tid >> 4, tx = tid & 15;
    const int lr = tid >> 2, lc = (tid & 3) << 2;   // loader: row, col(4-wide)

    float acc[4][4];
    #pragma unroll
    for (int m = 0; m < 4; ++m)
        #pragma unroll
        for (int n = 0; n < 4; ++n) acc[m][n] = 0.f;

    for (int d0 = 0; d0 < DD; d0 += 16) {
        float4 av = *(const float4*)(A + (size_t)(t0 + lr) * DD + d0 + lc);
        float4 bv = *(const float4*)(W + (size_t)(j0 + lr) * DD + d0 + lc);
        As[lr][lc] = av.x; As[lr][lc+1] = av.y; As[lr][lc+2] = av.z; As[lr][lc+3] = av.w;
        Bs[lr][lc] = bv.x; Bs[lr][lc+1] = bv.y; Bs[lr][lc+2] = bv.z; Bs[lr][lc+3] = bv.w;
        __syncthreads();
        #pragma unroll
        for (int kk = 0; kk < 16; ++kk) {
            float a[4], b[4];
            #pragma unroll
            for (int m = 0; m < 4; ++m) a[m] = As[ty*4+m][kk];
            #pragma unroll
            for (int n = 0; n < 4; ++n) b[n] = Bs[tx*4+n][kk];
            #pragma unroll
            for (int m = 0; m < 4; ++m)
                #pragma unroll
                for (int n = 0; n < 4; ++n) acc[m][n] += a[m]*b[n];
        }
        __syncthreads();
    }

    #pragma unroll
    for (int m = 0; m < 4; ++m) {
        float4 o;
        o.x = acc[m][0]; o.y = acc[m][1]; o.z = acc[m][2]; o.w = acc[m][3];
        if (bias) {
            o.x += bias[j0 + tx*4 + 0];
            o.y += bias[j0 + tx*4 + 1];
            o.z += bias[j0 + tx*4 + 2];
            o.w += bias[j0 + tx*4 + 3];
        }
        *(float4*)(C + (size_t)(t0 + ty*4 + m) * DD + j0 + tx*4) = o;
    }
}

// ---------------------------------------------------------------------------
// phi kernel: per token t -> pq = LN(elu(q)+1), pk = LN(elu(k)+1),
//             beta[t] = sigmoid(x . beta_w + beta_b)
// one block of 256 threads per token
// ---------------------------------------------------------------------------
__global__ __launch_bounds__(256)
void phi_kernel(const float* __restrict__ q, const float* __restrict__ k,
                const float* __restrict__ x, const float* __restrict__ beta_w,
                const float* __restrict__ beta_b,
                const float* __restrict__ lnp_g, const float* __restrict__ lnp_b,
                float* __restrict__ pq, float* __restrict__ pk,
                float* __restrict__ betas)
{
    const int t = blockIdx.x;
    const int j = threadIdx.x;
    const size_t base = (size_t)t * DD;

    float qv = q[base + j], kv = k[base + j], xv = x[base + j];
    float eq = qv > 0.f ? qv + 1.f : expf(qv);
    float ek = kv > 0.f ? kv + 1.f : expf(kv);
    float bd = xv * beta_w[j];

    float s0 = eq, s1 = eq*eq, s2 = ek, s3 = ek*ek, s4 = bd;
    #pragma unroll
    for (int off = 32; off; off >>= 1) {
        s0 += __shfl_xor(s0, off);
        s1 += __shfl_xor(s1, off);
        s2 += __shfl_xor(s2, off);
        s3 += __shfl_xor(s3, off);
        s4 += __shfl_xor(s4, off);
    }
    __shared__ float red[4][5];
    const int lane = j & 63, w = j >> 6;
    if (lane == 0) { red[w][0]=s0; red[w][1]=s1; red[w][2]=s2; red[w][3]=s3; red[w][4]=s4; }
    __syncthreads();
    float T0 = red[0][0]+red[1][0]+red[2][0]+red[3][0];
    float T1 = red[0][1]+red[1][1]+red[2][1]+red[3][1];
    float T2 = red[0][2]+red[1][2]+red[2][2]+red[3][2];
    float T3 = red[0][3]+red[1][3]+red[2][3]+red[3][3];
    float T4 = red[0][4]+red[1][4]+red[2][4]+red[3][4];

    float mu_q = T0 * (1.f/DD);
    float var_q = T1 * (1.f/DD) - mu_q*mu_q;
    float rs_q = rsqrtf(var_q + LN_EPS);
    float mu_k = T2 * (1.f/DD);
    float var_k = T3 * (1.f/DD) - mu_k*mu_k;
    float rs_k = rsqrtf(var_k + LN_EPS);

    pq[base + j] = (eq - mu_q) * rs_q * lnp_g[j] + lnp_b[j];
    pk[base + j] = (ek - mu_k) * rs_k * lnp_g[j] + lnp_b[j];
    if (j == 0) betas[t] = 1.f / (1.f + expf(-(T4 + beta_b[0])));
}

// ---------------------------------------------------------------------------
// LN kernel: per token LN(y) with ln_g, ln_b
// ---------------------------------------------------------------------------
__global__ __launch_bounds__(256)
void ln_kernel(const float* __restrict__ y, const float* __restrict__ g,
               const float* __restrict__ b, float* __restrict__ out)
{
    const int t = blockIdx.x;
    const int j = threadIdx.x;
    const size_t base = (size_t)t * DD;
    float v = y[base + j];
    float s0 = v, s1 = v*v;
    #pragma unroll
    for (int off = 32; off; off >>= 1) {
        s0 += __shfl_xor(s0, off);
        s1 += __shfl_xor(s1, off);
    }
    __shared__ float red[4][2];
    const int lane = j & 63, w = j >> 6;
    if (lane == 0) { red[w][0]=s0; red[w][1]=s1; }
    __syncthreads();
    float T0 = red[0][0]+red[1][0]+red[2][0]+red[3][0];
    float T1 = red[0][1]+red[1][1]+red[2][1]+red[3][1];
    float mu = T0 * (1.f/DD);
    float var = T1 * (1.f/DD) - mu*mu;
    float rs = rsqrtf(var + LN_EPS);
    out[base + j] = (v - mu) * rs * g[j] + b[j];
}

// ---------------------------------------------------------------------------
// Fast-weight recurrence. One wave per (b, i): state w_i = W[b][i][:] as
// float4/lane. Per step: r = w.phi_q, vb = w.phi_k reduced via DPP
// (row_shr 1/2/4/8 + row_bcast15/31 -> total in lane 63, 6 VALU-latency ops
// instead of 6 ds_bpermute). vr broadcast with v_readlane. Global loads
// prefetched 4 steps ahead (statically indexed regs).
// grid 256 blocks x 256 threads = 1024 waves.
// ---------------------------------------------------------------------------
__global__ __launch_bounds__(256)
void recur_kernel(const float* __restrict__ pq, const float* __restrict__ pk,
                  const float* __restrict__ v, const float* __restrict__ betas,
                  const float* __restrict__ decay, float* __restrict__ y)
{
    const int gtid = blockIdx.x * 256 + threadIdx.x;
    const int wid = gtid >> 6;          // 0..1023
    const int lane = threadIdx.x & 63;
    const int b = wid >> 8;             // batch
    const int i = wid & 255;            // row of W
    const float df = 1.f / (1.f + expf(-decay[0]));

    const float* pqb = pq + (size_t)b * LL * DD;
    const float* pkb = pk + (size_t)b * LL * DD;
    const float* vb_ = v  + (size_t)b * LL * DD;
    const float* bb  = betas + (size_t)b * LL;
    float* yb = y + (size_t)b * LL * DD;

    const int col = lane * 4;
    float4 w = make_float4(0.f, 0.f, 0.f, 0.f);

    const int PF = 4;                   // prefetch depth
    float4 qb[PF], kb[PF];
    float vib[PF], btb[PF];
    #pragma unroll
    for (int p = 0; p < PF; ++p) {
        qb[p] = *(const float4*)(pqb + (size_t)p * DD + col);
        kb[p] = *(const float4*)(pkb + (size_t)p * DD + col);
        vib[p] = vb_[(size_t)p * DD + i];
        btb[p] = bb[p];
    }

    for (int t0 = 0; t0 < LL; t0 += PF) {
        #pragma unroll
        for (int p = 0; p < PF; ++p) {
            const float4 q4 = qb[p], k4 = kb[p];
            const float vi = vib[p], bt = btb[p];

            // issue next prefetch early (covers L2 latency under ~PF steps)
            int tn = t0 + PF + p; if (tn > LL - 1) tn = LL - 1;
            qb[p] = *(const float4*)(pqb + (size_t)tn * DD + col);
            kb[p] = *(const float4*)(pkb + (size_t)tn * DD + col);
            vib[p] = vb_[(size_t)tn * DD + i];
            btb[p] = bb[tn];

            // per-lane partial dots (2-deep FMA trees)
            float r  = fmaf(w.x, q4.x, w.y * q4.y) + fmaf(w.z, q4.z, w.w * q4.w);
            float vr = fmaf(w.x, k4.x, w.y * k4.y) + fmaf(w.z, k4.z, w.w * k4.w);

            // DPP wave-64 sum (row_shr chain): total lands in lane 63.
            r  = DPP_ADD(r,  0x111);  vr = DPP_ADD(vr, 0x111);  // row_shr:1
            r  = DPP_ADD(r,  0x112);  vr = DPP_ADD(vr, 0x112);  // row_shr:2
            r  = DPP_ADD(r,  0x114);  vr = DPP_ADD(vr, 0x114);  // row_shr:4
            r  = DPP_ADD(r,  0x118);  vr = DPP_ADD(vr, 0x118);  // row_shr:8
            r  = DPP_ADD(r,  0x142);  vr = DPP_ADD(vr, 0x142);  // row_bcast15
            r  = DPP_ADD(r,  0x143);  vr = DPP_ADD(vr, 0x143);  // row_bcast31

            // broadcast vr (lane 63) to all lanes via readlane -> SGPR
            float vrt = __uint_as_float(
                (unsigned)__builtin_amdgcn_readlane(__float_as_uint(vr), 63));

            float u = bt * (vi - vrt);
            w.x = fmaf(df, w.x, u * k4.x);
            w.y = fmaf(df, w.y, u * k4.y);
            w.z = fmaf(df, w.z, u * k4.z);
            w.w = fmaf(df, w.w, u * k4.w);

            if (lane == 63) yb[(size_t)(t0 + p) * DD + i] = r;
        }
    }
}

// ---------------------------------------------------------------------------
extern "C" void kernel_launch(void* const* d_in, const int* in_sizes, int n_in,
                              void* d_out, int out_size, void* d_ws, size_t ws_size,
                              hipStream_t stream)
{
    const float* x      = (const float*)d_in[0];
    const float* Wq     = (const float*)d_in[1];
    const float* Wk     = (const float*)d_in[2];
    const float* Wv     = (const float*)d_in[3];
    const float* beta_w = (const float*)d_in[4];
    const float* beta_b = (const float*)d_in[5];
    const float* decay  = (const float*)d_in[6];
    const float* Wo     = (const float*)d_in[7];
    const float* bo     = (const float*)d_in[8];
    const float* ln_g   = (const float*)d_in[9];
    const float* ln_b   = (const float*)d_in[10];
    const float* lnp_g  = (const float*)d_in[11];
    const float* lnp_b  = (const float*)d_in[12];

    float* ws = (float*)d_ws;
    float* q_st  = ws + OFF_Y;     // q staging (reused later for y)
    float* k_st  = ws + OFF_LNY;   // k staging (reused later for ln(y))
    float* v_st  = ws + OFF_V;
    float* pq    = ws + OFF_PQ;
    float* pk    = ws + OFF_PK;
    float* betas = ws + OFF_BETA;

    dim3 gemm_grid(NT/64, DD/64);

    // projections
    gemm_nt_kernel<<<gemm_grid, 256, 0, stream>>>(x, Wq, nullptr, q_st);
    gemm_nt_kernel<<<gemm_grid, 256, 0, stream>>>(x, Wk, nullptr, k_st);
    gemm_nt_kernel<<<gemm_grid, 256, 0, stream>>>(x, Wv, nullptr, v_st);

    // phi + beta
    phi_kernel<<<NT, 256, 0, stream>>>(q_st, k_st, x, beta_w, beta_b,
                                       lnp_g, lnp_b, pq, pk, betas);

    // sequential fast-weight recurrence (y overwrites q staging)
    recur_kernel<<<256, 256, 0, stream>>>(pq, pk, v_st, betas, decay, ws + OFF_Y);

    // final LN (overwrites k staging) + output projection
    ln_kernel<<<NT, 256, 0, stream>>>(ws + OFF_Y, ln_g, ln_b, ws + OFF_LNY);
    gemm_nt_kernel<<<gemm_grid, 256, 0, stream>>>(ws + OFF_LNY, Wo, bo, (float*)d_out);
}

// Round 5
// 250.809 us; speedup vs baseline: 1.9016x; 1.0939x over previous
//
#include <hip/hip_runtime.h>
#include <math.h>

#define BB 4
#define LL 1024
#define DD 256
#define NT (BB*LL)          // 4096 tokens
#define LN_EPS 1e-5f

// workspace layout (floats)
#define OFF_PQ   0
#define OFF_PK   (NT*DD)
#define OFF_V    (2*NT*DD)
#define OFF_Y    (3*NT*DD)      // also q staging before phi
#define OFF_LNY  (4*NT*DD)      // also k staging before phi
#define OFF_BETA (5*NT*DD)

// DPP-assisted add: x + dpp_move(x, ctrl); invalid source lanes contribute 0
// (bound_ctrl=true). row_shr chain accumulates into lane 15 of each 16-row;
// row_bcast15/31 cascade row sums; total lands in lane 63.
#define DPP_ADD(x, ctrl) ((x) + __uint_as_float(__builtin_amdgcn_update_dpp( \
        0u, __float_as_uint(x), (ctrl), 0xf, 0xf, true)))

// ---------------------------------------------------------------------------
// GEMM: C[t][j] = sum_d A[t][d] * W[j][d]  (+ bias[j])   A:[NT x DD], W:[DD x DD]
// BM=64, BN=64, BK=16, 256 threads, 4x4 micro-tile
// ---------------------------------------------------------------------------
__global__ __launch_bounds__(256)
void gemm_nt_kernel(const float* __restrict__ A, const float* __restrict__ W,
                    const float* __restrict__ bias, float* __restrict__ C)
{
    __shared__ float As[64][17];
    __shared__ float Bs[64][17];
    const int tid = threadIdx.x;
    const int t0 = blockIdx.x * 64;
    const int j0 = blockIdx.y * 64;
    const int ty = tid >> 4, tx = tid & 15;
    const int lr = tid >> 2, lc = (tid & 3) << 2;   // loader: row, col(4-wide)

    float acc[4][4];
    #pragma unroll
    for (int m = 0; m < 4; ++m)
        #pragma unroll
        for (int n = 0; n < 4; ++n) acc[m][n] = 0.f;

    for (int d0 = 0; d0 < DD; d0 += 16) {
        float4 av = *(const float4*)(A + (size_t)(t0 + lr) * DD + d0 + lc);
        float4 bv = *(const float4*)(W + (size_t)(j0 + lr) * DD + d0 + lc);
        As[lr][lc] = av.x; As[lr][lc+1] = av.y; As[lr][lc+2] = av.z; As[lr][lc+3] = av.w;
        Bs[lr][lc] = bv.x; Bs[lr][lc+1] = bv.y; Bs[lr][lc+2] = bv.z; Bs[lr][lc+3] = bv.w;
        __syncthreads();
        #pragma unroll
        for (int kk = 0; kk < 16; ++kk) {
            float a[4], b[4];
            #pragma unroll
            for (int m = 0; m < 4; ++m) a[m] = As[ty*4+m][kk];
            #pragma unroll
            for (int n = 0; n < 4; ++n) b[n] = Bs[tx*4+n][kk];
            #pragma unroll
            for (int m = 0; m < 4; ++m)
                #pragma unroll
                for (int n = 0; n < 4; ++n) acc[m][n] += a[m]*b[n];
        }
        __syncthreads();
    }

    #pragma unroll
    for (int m = 0; m < 4; ++m) {
        float4 o;
        o.x = acc[m][0]; o.y = acc[m][1]; o.z = acc[m][2]; o.w = acc[m][3];
        if (bias) {
            o.x += bias[j0 + tx*4 + 0];
            o.y += bias[j0 + tx*4 + 1];
            o.z += bias[j0 + tx*4 + 2];
            o.w += bias[j0 + tx*4 + 3];
        }
        *(float4*)(C + (size_t)(t0 + ty*4 + m) * DD + j0 + tx*4) = o;
    }
}

// ---------------------------------------------------------------------------
// phi kernel: per token t -> pq = LN(elu(q)+1), pk = LN(elu(k)+1),
//             beta[t] = sigmoid(x . beta_w + beta_b)
// one block of 256 threads per token
// ---------------------------------------------------------------------------
__global__ __launch_bounds__(256)
void phi_kernel(const float* __restrict__ q, const float* __restrict__ k,
                const float* __restrict__ x, const float* __restrict__ beta_w,
                const float* __restrict__ beta_b,
                const float* __restrict__ lnp_g, const float* __restrict__ lnp_b,
                float* __restrict__ pq, float* __restrict__ pk,
                float* __restrict__ betas)
{
    const int t = blockIdx.x;
    const int j = threadIdx.x;
    const size_t base = (size_t)t * DD;

    float qv = q[base + j], kv = k[base + j], xv = x[base + j];
    float eq = qv > 0.f ? qv + 1.f : expf(qv);
    float ek = kv > 0.f ? kv + 1.f : expf(kv);
    float bd = xv * beta_w[j];

    float s0 = eq, s1 = eq*eq, s2 = ek, s3 = ek*ek, s4 = bd;
    #pragma unroll
    for (int off = 32; off; off >>= 1) {
        s0 += __shfl_xor(s0, off);
        s1 += __shfl_xor(s1, off);
        s2 += __shfl_xor(s2, off);
        s3 += __shfl_xor(s3, off);
        s4 += __shfl_xor(s4, off);
    }
    __shared__ float red[4][5];
    const int lane = j & 63, w = j >> 6;
    if (lane == 0) { red[w][0]=s0; red[w][1]=s1; red[w][2]=s2; red[w][3]=s3; red[w][4]=s4; }
    __syncthreads();
    float T0 = red[0][0]+red[1][0]+red[2][0]+red[3][0];
    float T1 = red[0][1]+red[1][1]+red[2][1]+red[3][1];
    float T2 = red[0][2]+red[1][2]+red[2][2]+red[3][2];
    float T3 = red[0][3]+red[1][3]+red[2][3]+red[3][3];
    float T4 = red[0][4]+red[1][4]+red[2][4]+red[3][4];

    float mu_q = T0 * (1.f/DD);
    float var_q = T1 * (1.f/DD) - mu_q*mu_q;
    float rs_q = rsqrtf(var_q + LN_EPS);
    float mu_k = T2 * (1.f/DD);
    float var_k = T3 * (1.f/DD) - mu_k*mu_k;
    float rs_k = rsqrtf(var_k + LN_EPS);

    pq[base + j] = (eq - mu_q) * rs_q * lnp_g[j] + lnp_b[j];
    pk[base + j] = (ek - mu_k) * rs_k * lnp_g[j] + lnp_b[j];
    if (j == 0) betas[t] = 1.f / (1.f + expf(-(T4 + beta_b[0])));
}

// ---------------------------------------------------------------------------
// LN kernel: per token LN(y) with ln_g, ln_b
// ---------------------------------------------------------------------------
__global__ __launch_bounds__(256)
void ln_kernel(const float* __restrict__ y, const float* __restrict__ g,
               const float* __restrict__ b, float* __restrict__ out)
{
    const int t = blockIdx.x;
    const int j = threadIdx.x;
    const size_t base = (size_t)t * DD;
    float v = y[base + j];
    float s0 = v, s1 = v*v;
    #pragma unroll
    for (int off = 32; off; off >>= 1) {
        s0 += __shfl_xor(s0, off);
        s1 += __shfl_xor(s1, off);
    }
    __shared__ float red[4][2];
    const int lane = j & 63, w = j >> 6;
    if (lane == 0) { red[w][0]=s0; red[w][1]=s1; }
    __syncthreads();
    float T0 = red[0][0]+red[1][0]+red[2][0]+red[3][0];
    float T1 = red[0][1]+red[1][1]+red[2][1]+red[3][1];
    float mu = T0 * (1.f/DD);
    float var = T1 * (1.f/DD) - mu*mu;
    float rs = rsqrtf(var + LN_EPS);
    out[base + j] = (v - mu) * rs * g[j] + b[j];
}

// ---------------------------------------------------------------------------
// Fast-weight recurrence. One wave per (b, i): state w_i = W[b][i][:] as
// float4/lane. DPP row_shr reduction (total in lane 63), readlane broadcast.
// XCD-aware block swizzle: blockIdx%8 = XCD; vblk = xcd*32+slot puts each
// batch b's 64 blocks on 2 XCDs -> per-XCD L2 hot set = pq[b]+pk[b] = 2MB
// (fits 4MB). Prefetch 8 steps ahead (statically indexed regs).
// grid 256 blocks x 256 threads = 1024 waves.
// ---------------------------------------------------------------------------
__global__ __launch_bounds__(256)
void recur_kernel(const float* __restrict__ pq, const float* __restrict__ pk,
                  const float* __restrict__ v, const float* __restrict__ betas,
                  const float* __restrict__ decay, float* __restrict__ y)
{
    // XCD swizzle (bijective on 0..255: 256 = 8 XCDs * 32 slots)
    const int xcd  = blockIdx.x & 7;
    const int slot = blockIdx.x >> 3;
    const int vblk = xcd * 32 + slot;

    const int gtid = vblk * 256 + threadIdx.x;
    const int wid = gtid >> 6;          // 0..1023
    const int lane = threadIdx.x & 63;
    const int b = wid >> 8;             // batch (contiguous per-XCD now)
    const int i = wid & 255;            // row of W
    const float df = 1.f / (1.f + expf(-decay[0]));

    const float* pqb = pq + (size_t)b * LL * DD;
    const float* pkb = pk + (size_t)b * LL * DD;
    const float* vb_ = v  + (size_t)b * LL * DD;
    const float* bb  = betas + (size_t)b * LL;
    float* yb = y + (size_t)b * LL * DD;

    const int col = lane * 4;
    float4 w = make_float4(0.f, 0.f, 0.f, 0.f);

    const int PF = 8;                   // prefetch depth
    float4 qb[PF], kb[PF];
    float vib[PF], btb[PF];
    #pragma unroll
    for (int p = 0; p < PF; ++p) {
        qb[p] = *(const float4*)(pqb + (size_t)p * DD + col);
        kb[p] = *(const float4*)(pkb + (size_t)p * DD + col);
        vib[p] = vb_[(size_t)p * DD + i];
        btb[p] = bb[p];
    }

    for (int t0 = 0; t0 < LL; t0 += PF) {
        #pragma unroll
        for (int p = 0; p < PF; ++p) {
            const float4 q4 = qb[p], k4 = kb[p];
            const float vi = vib[p], bt = btb[p];

            // issue next prefetch early (covers L2 latency under ~PF steps)
            int tn = t0 + PF + p; if (tn > LL - 1) tn = LL - 1;
            qb[p] = *(const float4*)(pqb + (size_t)tn * DD + col);
            kb[p] = *(const float4*)(pkb + (size_t)tn * DD + col);
            vib[p] = vb_[(size_t)tn * DD + i];
            btb[p] = bb[tn];

            // per-lane partial dots (2-deep FMA trees)
            float r  = fmaf(w.x, q4.x, w.y * q4.y) + fmaf(w.z, q4.z, w.w * q4.w);
            float vr = fmaf(w.x, k4.x, w.y * k4.y) + fmaf(w.z, k4.z, w.w * k4.w);

            // DPP wave-64 sum (row_shr chain): total lands in lane 63.
            r  = DPP_ADD(r,  0x111);  vr = DPP_ADD(vr, 0x111);  // row_shr:1
            r  = DPP_ADD(r,  0x112);  vr = DPP_ADD(vr, 0x112);  // row_shr:2
            r  = DPP_ADD(r,  0x114);  vr = DPP_ADD(vr, 0x114);  // row_shr:4
            r  = DPP_ADD(r,  0x118);  vr = DPP_ADD(vr, 0x118);  // row_shr:8
            r  = DPP_ADD(r,  0x142);  vr = DPP_ADD(vr, 0x142);  // row_bcast15
            r  = DPP_ADD(r,  0x143);  vr = DPP_ADD(vr, 0x143);  // row_bcast31

            // broadcast vr (lane 63) to all lanes via readlane -> SGPR
            float vrt = __uint_as_float(
                (unsigned)__builtin_amdgcn_readlane(__float_as_uint(vr), 63));

            float u = bt * (vi - vrt);
            w.x = fmaf(df, w.x, u * k4.x);
            w.y = fmaf(df, w.y, u * k4.y);
            w.z = fmaf(df, w.z, u * k4.z);
            w.w = fmaf(df, w.w, u * k4.w);

            if (lane == 63) yb[(size_t)(t0 + p) * DD + i] = r;
        }
    }
}

// ---------------------------------------------------------------------------
extern "C" void kernel_launch(void* const* d_in, const int* in_sizes, int n_in,
                              void* d_out, int out_size, void* d_ws, size_t ws_size,
                              hipStream_t stream)
{
    const float* x      = (const float*)d_in[0];
    const float* Wq     = (const float*)d_in[1];
    const float* Wk     = (const float*)d_in[2];
    const float* Wv     = (const float*)d_in[3];
    const float* beta_w = (const float*)d_in[4];
    const float* beta_b = (const float*)d_in[5];
    const float* decay  = (const float*)d_in[6];
    const float* Wo     = (const float*)d_in[7];
    const float* bo     = (const float*)d_in[8];
    const float* ln_g   = (const float*)d_in[9];
    const float* ln_b   = (const float*)d_in[10];
    const float* lnp_g  = (const float*)d_in[11];
    const float* lnp_b  = (const float*)d_in[12];

    float* ws = (float*)d_ws;
    float* q_st  = ws + OFF_Y;     // q staging (reused later for y)
    float* k_st  = ws + OFF_LNY;   // k staging (reused later for ln(y))
    float* v_st  = ws + OFF_V;
    float* pq    = ws + OFF_PQ;
    float* pk    = ws + OFF_PK;
    float* betas = ws + OFF_BETA;

    dim3 gemm_grid(NT/64, DD/64);

    // projections
    gemm_nt_kernel<<<gemm_grid, 256, 0, stream>>>(x, Wq, nullptr, q_st);
    gemm_nt_kernel<<<gemm_grid, 256, 0, stream>>>(x, Wk, nullptr, k_st);
    gemm_nt_kernel<<<gemm_grid, 256, 0, stream>>>(x, Wv, nullptr, v_st);

    // phi + beta
    phi_kernel<<<NT, 256, 0, stream>>>(q_st, k_st, x, beta_w, beta_b,
                                       lnp_g, lnp_b, pq, pk, betas);

    // sequential fast-weight recurrence (y overwrites q staging)
    recur_kernel<<<256, 256, 0, stream>>>(pq, pk, v_st, betas, decay, ws + OFF_Y);

    // final LN (overwrites k staging) + output projection
    ln_kernel<<<NT, 256, 0, stream>>>(ws + OFF_Y, ln_g, ln_b, ws + OFF_LNY);
    gemm_nt_kernel<<<gemm_grid, 256, 0, stream>>>(ws + OFF_LNY, Wo, bo, (float*)d_out);
}

// Round 6
// 236.131 us; speedup vs baseline: 2.0198x; 1.0622x over previous
//
#include <hip/hip_runtime.h>
#include <math.h>

#define BB 4
#define LL 1024
#define DD 256
#define NT (BB*LL)          // 4096 tokens
#define LN_EPS 1e-5f

// workspace layout (floats)
#define OFF_PQ   0
#define OFF_PK   (NT*DD)
#define OFF_V    (2*NT*DD)      // becomes beta*v after phi (in-place)
#define OFF_Y    (3*NT*DD)      // also q staging before phi
#define OFF_LNY  (4*NT*DD)      // also k staging before phi
#define OFF_BETA (5*NT*DD)
#define OFF_BAND (5*NT*DD + NT) // NT*8 floats: {G1,G2,G3,0, H1,H2,H3,beta}

// DPP-assisted add: x + dpp_move(x, ctrl); invalid source lanes contribute 0
// (bound_ctrl=true). row_shr 1/2/4/8 accumulates row sums into lanes
// 15/31/47/63; row_bcast15 then row_bcast31 cascade them; total in lane 63.
#define DPP_ADD(x, ctrl) ((x) + __uint_as_float(__builtin_amdgcn_update_dpp( \
        0u, __float_as_uint(x), (ctrl), 0xf, 0xf, true)))

__device__ __forceinline__ float dot4f(float4 a, float4 b) {
    return fmaf(a.x, b.x, a.y * b.y) + fmaf(a.z, b.z, a.w * b.w);
}
__device__ __forceinline__ float rdl63(float x) {
    return __uint_as_float((unsigned)__builtin_amdgcn_readlane(__float_as_uint(x), 63));
}

// ---------------------------------------------------------------------------
// GEMM core: C[t][j] = sum_d A[t][d] * W[j][d] (+bias). BM=64,BN=64,BK=16.
// ---------------------------------------------------------------------------
__device__ __forceinline__
void gemm_body(const float* __restrict__ A, const float* __restrict__ W,
               const float* __restrict__ bias, float* __restrict__ C,
               int t0, int j0)
{
    __shared__ float As[64][17];
    __shared__ float Bs[64][17];
    const int tid = threadIdx.x;
    const int ty = tid >> 4, tx = tid & 15;
    const int lr = tid >> 2, lc = (tid & 3) << 2;

    float acc[4][4];
    #pragma unroll
    for (int m = 0; m < 4; ++m)
        #pragma unroll
        for (int n = 0; n < 4; ++n) acc[m][n] = 0.f;

    for (int d0 = 0; d0 < DD; d0 += 16) {
        float4 av = *(const float4*)(A + (size_t)(t0 + lr) * DD + d0 + lc);
        float4 bv = *(const float4*)(W + (size_t)(j0 + lr) * DD + d0 + lc);
        As[lr][lc] = av.x; As[lr][lc+1] = av.y; As[lr][lc+2] = av.z; As[lr][lc+3] = av.w;
        Bs[lr][lc] = bv.x; Bs[lr][lc+1] = bv.y; Bs[lr][lc+2] = bv.z; Bs[lr][lc+3] = bv.w;
        __syncthreads();
        #pragma unroll
        for (int kk = 0; kk < 16; ++kk) {
            float a[4], b[4];
            #pragma unroll
            for (int m = 0; m < 4; ++m) a[m] = As[ty*4+m][kk];
            #pragma unroll
            for (int n = 0; n < 4; ++n) b[n] = Bs[tx*4+n][kk];
            #pragma unroll
            for (int m = 0; m < 4; ++m)
                #pragma unroll
                for (int n = 0; n < 4; ++n) acc[m][n] += a[m]*b[n];
        }
        __syncthreads();
    }

    #pragma unroll
    for (int m = 0; m < 4; ++m) {
        float4 o;
        o.x = acc[m][0]; o.y = acc[m][1]; o.z = acc[m][2]; o.w = acc[m][3];
        if (bias) {
            o.x += bias[j0 + tx*4 + 0];
            o.y += bias[j0 + tx*4 + 1];
            o.z += bias[j0 + tx*4 + 2];
            o.w += bias[j0 + tx*4 + 3];
        }
        *(float4*)(C + (size_t)(t0 + ty*4 + m) * DD + j0 + tx*4) = o;
    }
}

__global__ __launch_bounds__(256)
void gemm_qkv_kernel(const float* __restrict__ x,
                     const float* __restrict__ Wq, const float* __restrict__ Wk,
                     const float* __restrict__ Wv,
                     float* __restrict__ q, float* __restrict__ k, float* __restrict__ v)
{
    const float* W = (blockIdx.z == 0) ? Wq : (blockIdx.z == 1) ? Wk : Wv;
    float*       C = (blockIdx.z == 0) ? q  : (blockIdx.z == 1) ? k  : v;
    gemm_body(x, W, nullptr, C, blockIdx.x * 64, blockIdx.y * 64);
}

__global__ __launch_bounds__(256)
void gemm_nt_kernel(const float* __restrict__ A, const float* __restrict__ W,
                    const float* __restrict__ bias, float* __restrict__ C)
{
    gemm_body(A, W, bias, C, blockIdx.x * 64, blockIdx.y * 64);
}

// ---------------------------------------------------------------------------
// phi: pq = LN(elu(q)+1), pk = LN(elu(k)+1); beta = sigmoid(x.bw + bb);
// v *= beta (in place); betas[t] = beta. One 256-thread block per token.
// ---------------------------------------------------------------------------
__global__ __launch_bounds__(256)
void phi_kernel(const float* __restrict__ q, const float* __restrict__ k,
                const float* __restrict__ x, float* __restrict__ v,
                const float* __restrict__ beta_w, const float* __restrict__ beta_b,
                const float* __restrict__ lnp_g, const float* __restrict__ lnp_b,
                float* __restrict__ pq, float* __restrict__ pk,
                float* __restrict__ betas)
{
    const int t = blockIdx.x;
    const int j = threadIdx.x;
    const size_t base = (size_t)t * DD;

    float qv = q[base + j], kv = k[base + j], xv = x[base + j];
    float eq = qv > 0.f ? qv + 1.f : expf(qv);
    float ek = kv > 0.f ? kv + 1.f : expf(kv);
    float bd = xv * beta_w[j];

    float s0 = eq, s1 = eq*eq, s2 = ek, s3 = ek*ek, s4 = bd;
    #pragma unroll
    for (int off = 32; off; off >>= 1) {
        s0 += __shfl_xor(s0, off);
        s1 += __shfl_xor(s1, off);
        s2 += __shfl_xor(s2, off);
        s3 += __shfl_xor(s3, off);
        s4 += __shfl_xor(s4, off);
    }
    __shared__ float red[4][5];
    const int lane = j & 63, w = j >> 6;
    if (lane == 0) { red[w][0]=s0; red[w][1]=s1; red[w][2]=s2; red[w][3]=s3; red[w][4]=s4; }
    __syncthreads();
    float T0 = red[0][0]+red[1][0]+red[2][0]+red[3][0];
    float T1 = red[0][1]+red[1][1]+red[2][1]+red[3][1];
    float T2 = red[0][2]+red[1][2]+red[2][2]+red[3][2];
    float T3 = red[0][3]+red[1][3]+red[2][3]+red[3][3];
    float T4 = red[0][4]+red[1][4]+red[2][4]+red[3][4];

    float mu_q = T0 * (1.f/DD);
    float var_q = T1 * (1.f/DD) - mu_q*mu_q;
    float rs_q = rsqrtf(var_q + LN_EPS);
    float mu_k = T2 * (1.f/DD);
    float var_k = T3 * (1.f/DD) - mu_k*mu_k;
    float rs_k = rsqrtf(var_k + LN_EPS);

    pq[base + j] = (eq - mu_q) * rs_q * lnp_g[j] + lnp_b[j];
    pk[base + j] = (ek - mu_k) * rs_k * lnp_g[j] + lnp_b[j];

    float beta = 1.f / (1.f + expf(-(T4 + beta_b[0])));
    v[base + j] *= beta;                 // v becomes beta*v
    if (j == 0) betas[t] = beta;
}

// ---------------------------------------------------------------------------
// band: per token t (within batch), G_m = df^{m-1} * (pk[t-m].pk[t]),
// H_m = df^{m-1} * (pk[t-m].pq[t]) for m=1..3 (0 if t-m<0).
// Layout band[g][8] = {G1,G2,G3,0, H1,H2,H3,beta}. One wave per token.
// ---------------------------------------------------------------------------
__global__ __launch_bounds__(256)
void band_kernel(const float* __restrict__ pq, const float* __restrict__ pk,
                 const float* __restrict__ betas, const float* __restrict__ decay,
                 float* __restrict__ band)
{
    const int wv = threadIdx.x >> 6, lane = threadIdx.x & 63;
    const int g = blockIdx.x * 4 + wv;       // global token 0..NT-1
    const int tt = g & (LL - 1);             // token index within batch
    const int col = lane * 4;
    const float df = 1.f / (1.f + expf(-decay[0]));

    float4 kv = *(const float4*)(pk + (size_t)g * DD + col);
    float4 qv = *(const float4*)(pq + (size_t)g * DD + col);

    float G[3], H[3];
    float dfp = 1.f;
    #pragma unroll
    for (int m = 1; m <= 3; ++m) {
        float4 km = make_float4(0.f, 0.f, 0.f, 0.f);
        if (tt >= m) km = *(const float4*)(pk + (size_t)(g - m) * DD + col);
        float gg = dot4f(km, kv), hh = dot4f(km, qv);
        gg = DPP_ADD(gg, 0x111);  hh = DPP_ADD(hh, 0x111);
        gg = DPP_ADD(gg, 0x112);  hh = DPP_ADD(hh, 0x112);
        gg = DPP_ADD(gg, 0x114);  hh = DPP_ADD(hh, 0x114);
        gg = DPP_ADD(gg, 0x118);  hh = DPP_ADD(hh, 0x118);
        gg = DPP_ADD(gg, 0x142);  hh = DPP_ADD(hh, 0x142);
        gg = DPP_ADD(gg, 0x143);  hh = DPP_ADD(hh, 0x143);
        G[m-1] = dfp * rdl63(gg);
        H[m-1] = dfp * rdl63(hh);
        dfp *= df;
    }
    if (lane == 0) {
        float4 a = make_float4(G[0], G[1], G[2], 0.f);
        float4 bvec = make_float4(H[0], H[1], H[2], betas[g]);
        *(float4*)(band + (size_t)g * 8)     = a;
        *(float4*)(band + (size_t)g * 8 + 4) = bvec;
    }
}

// ---------------------------------------------------------------------------
// Fast-weight recurrence, block-4 lookahead. One wave per (b,i).
// Per block: 8 dots vs block-invariant w_base + 8 pipelined DPP reductions;
// scalar recursion chain = 2 dependent FMAs/step using precomputed band;
// state advanced 4 steps at once. Ping-pong register buffers, 1-block
// prefetch. XCD swizzle keeps each batch's streams in one XCD's L2.
// ---------------------------------------------------------------------------
#define RED8(c) s0=DPP_ADD(s0,c); s1=DPP_ADD(s1,c); s2=DPP_ADD(s2,c); s3=DPP_ADD(s3,c); \
                p0=DPP_ADD(p0,c); p1=DPP_ADD(p1,c); p2=DPP_ADD(p2,c); p3=DPP_ADD(p3,c);

#define STEP4(T0, qA, kA, bA0, bA1, vA, qB, kB, bB0, bB1, vB)                   \
  {                                                                             \
    float s0 = dot4f(w, kA[0]),       p0 = dot4f(w, qA[0]);                     \
    float s1 = dot4f(w, kA[1]) * df,  p1 = dot4f(w, qA[1]) * df;                \
    float s2 = dot4f(w, kA[2]) * df2, p2 = dot4f(w, qA[2]) * df2;               \
    float s3 = dot4f(w, kA[3]) * df3, p3 = dot4f(w, qA[3]) * df3;               \
    RED8(0x111) RED8(0x112) RED8(0x114) RED8(0x118) RED8(0x142) RED8(0x143)     \
    const float S0 = rdl63(s0), S1 = rdl63(s1), S2 = rdl63(s2), S3 = rdl63(s3); \
    const float P0 = rdl63(p0), P1 = rdl63(p1), P2 = rdl63(p2), P3 = rdl63(p3); \
    {   /* prefetch next block into B buffers */                                \
        int tn = (T0) + 4; if (tn > LL - 4) tn = LL - 4;                        \
        _Pragma("unroll")                                                       \
        for (int pp = 0; pp < 4; ++pp) {                                        \
            qB[pp]  = *(const float4*)(pqb + (size_t)(tn+pp)*DD + col);         \
            kB[pp]  = *(const float4*)(pkb + (size_t)(tn+pp)*DD + col);         \
            bB0[pp] = *(const float4*)(bdb + (size_t)(tn+pp)*8);                \
            bB1[pp] = *(const float4*)(bdb + (size_t)(tn+pp)*8 + 4);            \
            vB[pp]  = vbb[(size_t)(tn+pp)*DD + i];                              \
        }                                                                       \
    }                                                                           \
    const float u0v = fmaf(-bA1[0].w, S0, vA[0]);                               \
    const float rr0 = P0;                                                       \
    const float vr1 = fmaf(bA0[1].x, u0v, S1);                                  \
    const float rr1 = fmaf(bA1[1].x, u0v, P1);                                  \
    const float u1v = fmaf(-bA1[1].w, vr1, vA[1]);                              \
    const float vr2 = fmaf(bA0[2].x, u1v, fmaf(bA0[2].y, u0v, S2));             \
    const float rr2 = fmaf(bA1[2].x, u1v, fmaf(bA1[2].y, u0v, P2));             \
    const float u2v = fmaf(-bA1[2].w, vr2, vA[2]);                              \
    const float vr3 = fmaf(bA0[3].x, u2v, fmaf(bA0[3].y, u1v, fmaf(bA0[3].z, u0v, S3))); \
    const float rr3 = fmaf(bA1[3].x, u2v, fmaf(bA1[3].y, u1v, fmaf(bA1[3].z, u0v, P3))); \
    const float u3v = fmaf(-bA1[3].w, vr3, vA[3]);                              \
    float4 acc;                                                                 \
    acc.x = u0v*kA[0].x; acc.y = u0v*kA[0].y; acc.z = u0v*kA[0].z; acc.w = u0v*kA[0].w; \
    acc.x = fmaf(df, acc.x, u1v*kA[1].x); acc.y = fmaf(df, acc.y, u1v*kA[1].y); \
    acc.z = fmaf(df, acc.z, u1v*kA[1].z); acc.w = fmaf(df, acc.w, u1v*kA[1].w); \
    acc.x = fmaf(df, acc.x, u2v*kA[2].x); acc.y = fmaf(df, acc.y, u2v*kA[2].y); \
    acc.z = fmaf(df, acc.z, u2v*kA[2].z); acc.w = fmaf(df, acc.w, u2v*kA[2].w); \
    acc.x = fmaf(df, acc.x, u3v*kA[3].x); acc.y = fmaf(df, acc.y, u3v*kA[3].y); \
    acc.z = fmaf(df, acc.z, u3v*kA[3].z); acc.w = fmaf(df, acc.w, u3v*kA[3].w); \
    w.x = fmaf(df4, w.x, acc.x); w.y = fmaf(df4, w.y, acc.y);                   \
    w.z = fmaf(df4, w.z, acc.z); w.w = fmaf(df4, w.w, acc.w);                   \
    if (lane == 0) {                                                            \
        yb[(size_t)((T0)+0)*DD + i] = rr0;                                      \
        yb[(size_t)((T0)+1)*DD + i] = rr1;                                      \
        yb[(size_t)((T0)+2)*DD + i] = rr2;                                      \
        yb[(size_t)((T0)+3)*DD + i] = rr3;                                      \
    }                                                                           \
  }

__global__ __launch_bounds__(256)
void recur_kernel(const float* __restrict__ pq, const float* __restrict__ pk,
                  const float* __restrict__ vbeta, const float* __restrict__ band,
                  const float* __restrict__ decay, float* __restrict__ y)
{
    // XCD swizzle (bijective on 0..255)
    const int xcd  = blockIdx.x & 7;
    const int slot = blockIdx.x >> 3;
    const int vblk = xcd * 32 + slot;

    const int gtid = vblk * 256 + threadIdx.x;
    const int wid  = gtid >> 6;
    const int lane = threadIdx.x & 63;
    const int b = wid >> 8;
    const int i = wid & 255;

    const float df  = 1.f / (1.f + expf(-decay[0]));
    const float df2 = df * df, df3 = df2 * df, df4 = df2 * df2;

    const float* pqb = pq    + (size_t)b * LL * DD;
    const float* pkb = pk    + (size_t)b * LL * DD;
    const float* vbb = vbeta + (size_t)b * LL * DD;
    const float* bdb = band  + (size_t)b * LL * 8;
    float* yb = y + (size_t)b * LL * DD;
    const int col = lane * 4;

    float4 w = make_float4(0.f, 0.f, 0.f, 0.f);

    float4 qA[4], kA[4], bA0[4], bA1[4]; float vA[4];
    float4 qB[4], kB[4], bB0[4], bB1[4]; float vB[4];

    #pragma unroll
    for (int p = 0; p < 4; ++p) {
        qA[p]  = *(const float4*)(pqb + (size_t)p * DD + col);
        kA[p]  = *(const float4*)(pkb + (size_t)p * DD + col);
        bA0[p] = *(const float4*)(bdb + (size_t)p * 8);
        bA1[p] = *(const float4*)(bdb + (size_t)p * 8 + 4);
        vA[p]  = vbb[(size_t)p * DD + i];
    }

    for (int t0 = 0; t0 < LL; t0 += 8) {
        STEP4(t0,     qA, kA, bA0, bA1, vA, qB, kB, bB0, bB1, vB)
        STEP4(t0 + 4, qB, kB, bB0, bB1, vB, qA, kA, bA0, bA1, vA)
    }
}

// ---------------------------------------------------------------------------
// LN kernel: per token LN(y) with ln_g, ln_b
// ---------------------------------------------------------------------------
__global__ __launch_bounds__(256)
void ln_kernel(const float* __restrict__ y, const float* __restrict__ g,
               const float* __restrict__ b, float* __restrict__ out)
{
    const int t = blockIdx.x;
    const int j = threadIdx.x;
    const size_t base = (size_t)t * DD;
    float v = y[base + j];
    float s0 = v, s1 = v*v;
    #pragma unroll
    for (int off = 32; off; off >>= 1) {
        s0 += __shfl_xor(s0, off);
        s1 += __shfl_xor(s1, off);
    }
    __shared__ float red[4][2];
    const int lane = j & 63, w = j >> 6;
    if (lane == 0) { red[w][0]=s0; red[w][1]=s1; }
    __syncthreads();
    float T0 = red[0][0]+red[1][0]+red[2][0]+red[3][0];
    float T1 = red[0][1]+red[1][1]+red[2][1]+red[3][1];
    float mu = T0 * (1.f/DD);
    float var = T1 * (1.f/DD) - mu*mu;
    float rs = rsqrtf(var + LN_EPS);
    out[base + j] = (v - mu) * rs * g[j] + b[j];
}

// ---------------------------------------------------------------------------
extern "C" void kernel_launch(void* const* d_in, const int* in_sizes, int n_in,
                              void* d_out, int out_size, void* d_ws, size_t ws_size,
                              hipStream_t stream)
{
    const float* x      = (const float*)d_in[0];
    const float* Wq     = (const float*)d_in[1];
    const float* Wk     = (const float*)d_in[2];
    const float* Wv     = (const float*)d_in[3];
    const float* beta_w = (const float*)d_in[4];
    const float* beta_b = (const float*)d_in[5];
    const float* decay  = (const float*)d_in[6];
    const float* Wo     = (const float*)d_in[7];
    const float* bo     = (const float*)d_in[8];
    const float* ln_g   = (const float*)d_in[9];
    const float* ln_b   = (const float*)d_in[10];
    const float* lnp_g  = (const float*)d_in[11];
    const float* lnp_b  = (const float*)d_in[12];

    float* ws = (float*)d_ws;
    float* q_st  = ws + OFF_Y;
    float* k_st  = ws + OFF_LNY;
    float* v_st  = ws + OFF_V;     // scaled to beta*v by phi
    float* pq    = ws + OFF_PQ;
    float* pk    = ws + OFF_PK;
    float* betas = ws + OFF_BETA;
    float* band  = ws + OFF_BAND;

    // fused q/k/v projections
    gemm_qkv_kernel<<<dim3(NT/64, DD/64, 3), 256, 0, stream>>>(
        x, Wq, Wk, Wv, q_st, k_st, v_st);

    // phi + beta (+ v *= beta in place)
    phi_kernel<<<NT, 256, 0, stream>>>(q_st, k_st, x, v_st, beta_w, beta_b,
                                       lnp_g, lnp_b, pq, pk, betas);

    // Gram band (fully parallel)
    band_kernel<<<NT/4, 256, 0, stream>>>(pq, pk, betas, decay, band);

    // sequential fast-weight recurrence (block-4 lookahead)
    recur_kernel<<<256, 256, 0, stream>>>(pq, pk, v_st, band, decay, ws + OFF_Y);

    // final LN + output projection
    ln_kernel<<<NT, 256, 0, stream>>>(ws + OFF_Y, ln_g, ln_b, ws + OFF_LNY);
    gemm_nt_kernel<<<dim3(NT/64, DD/64), 256, 0, stream>>>(ws + OFF_LNY, Wo, bo, (float*)d_out);
}

// Round 7
// 234.384 us; speedup vs baseline: 2.0349x; 1.0075x over previous
//
#include <hip/hip_runtime.h>
#include <math.h>

#define BB 4
#define LL 1024
#define DD 256
#define NT (BB*LL)          // 4096 tokens
#define LN_EPS 1e-5f

// workspace layout (floats)
#define OFF_PQ   0
#define OFF_PK   (NT*DD)
#define OFF_V    (2*NT*DD)      // becomes beta*v after phi (in-place)
#define OFF_Y    (3*NT*DD)      // also q staging before phi
#define OFF_LNY  (4*NT*DD)      // also k staging before phi
#define OFF_BETA (5*NT*DD)
#define OFF_BAND (5*NT*DD + NT) // NT*8 floats: {G1,G2,G3,0, H1,H2,H3,beta}

// DPP-assisted add: x + dpp_move(x, ctrl); invalid source lanes contribute 0
// (bound_ctrl=true). row_shr 1/2/4/8 accumulates row sums into lanes
// 15/31/47/63; row_bcast15 then row_bcast31 cascade them; total in lane 63.
#define DPP_ADD(x, ctrl) ((x) + __uint_as_float(__builtin_amdgcn_update_dpp( \
        0u, __float_as_uint(x), (ctrl), 0xf, 0xf, true)))

__device__ __forceinline__ float dot4f(float4 a, float4 b) {
    return fmaf(a.x, b.x, a.y * b.y) + fmaf(a.z, b.z, a.w * b.w);
}
__device__ __forceinline__ float rdl63(float x) {
    return __uint_as_float((unsigned)__builtin_amdgcn_readlane(__float_as_uint(x), 63));
}

// ---------------------------------------------------------------------------
// GEMM core: C[t][j] = sum_d A[t][d] * W[j][d] (+bias). BM=64,BN=64,BK=16.
// ---------------------------------------------------------------------------
__device__ __forceinline__
void gemm_body(const float* __restrict__ A, const float* __restrict__ W,
               const float* __restrict__ bias, float* __restrict__ C,
               int t0, int j0)
{
    __shared__ float As[64][17];
    __shared__ float Bs[64][17];
    const int tid = threadIdx.x;
    const int ty = tid >> 4, tx = tid & 15;
    const int lr = tid >> 2, lc = (tid & 3) << 2;

    float acc[4][4];
    #pragma unroll
    for (int m = 0; m < 4; ++m)
        #pragma unroll
        for (int n = 0; n < 4; ++n) acc[m][n] = 0.f;

    for (int d0 = 0; d0 < DD; d0 += 16) {
        float4 av = *(const float4*)(A + (size_t)(t0 + lr) * DD + d0 + lc);
        float4 bv = *(const float4*)(W + (size_t)(j0 + lr) * DD + d0 + lc);
        As[lr][lc] = av.x; As[lr][lc+1] = av.y; As[lr][lc+2] = av.z; As[lr][lc+3] = av.w;
        Bs[lr][lc] = bv.x; Bs[lr][lc+1] = bv.y; Bs[lr][lc+2] = bv.z; Bs[lr][lc+3] = bv.w;
        __syncthreads();
        #pragma unroll
        for (int kk = 0; kk < 16; ++kk) {
            float a[4], b[4];
            #pragma unroll
            for (int m = 0; m < 4; ++m) a[m] = As[ty*4+m][kk];
            #pragma unroll
            for (int n = 0; n < 4; ++n) b[n] = Bs[tx*4+n][kk];
            #pragma unroll
            for (int m = 0; m < 4; ++m)
                #pragma unroll
                for (int n = 0; n < 4; ++n) acc[m][n] += a[m]*b[n];
        }
        __syncthreads();
    }

    #pragma unroll
    for (int m = 0; m < 4; ++m) {
        float4 o;
        o.x = acc[m][0]; o.y = acc[m][1]; o.z = acc[m][2]; o.w = acc[m][3];
        if (bias) {
            o.x += bias[j0 + tx*4 + 0];
            o.y += bias[j0 + tx*4 + 1];
            o.z += bias[j0 + tx*4 + 2];
            o.w += bias[j0 + tx*4 + 3];
        }
        *(float4*)(C + (size_t)(t0 + ty*4 + m) * DD + j0 + tx*4) = o;
    }
}

__global__ __launch_bounds__(256)
void gemm_qkv_kernel(const float* __restrict__ x,
                     const float* __restrict__ Wq, const float* __restrict__ Wk,
                     const float* __restrict__ Wv,
                     float* __restrict__ q, float* __restrict__ k, float* __restrict__ v)
{
    const float* W = (blockIdx.z == 0) ? Wq : (blockIdx.z == 1) ? Wk : Wv;
    float*       C = (blockIdx.z == 0) ? q  : (blockIdx.z == 1) ? k  : v;
    gemm_body(x, W, nullptr, C, blockIdx.x * 64, blockIdx.y * 64);
}

__global__ __launch_bounds__(256)
void gemm_nt_kernel(const float* __restrict__ A, const float* __restrict__ W,
                    const float* __restrict__ bias, float* __restrict__ C)
{
    gemm_body(A, W, bias, C, blockIdx.x * 64, blockIdx.y * 64);
}

// ---------------------------------------------------------------------------
// phi: pq = LN(elu(q)+1), pk = LN(elu(k)+1); beta = sigmoid(x.bw + bb);
// v *= beta (in place); betas[t] = beta. One 256-thread block per token.
// ---------------------------------------------------------------------------
__global__ __launch_bounds__(256)
void phi_kernel(const float* __restrict__ q, const float* __restrict__ k,
                const float* __restrict__ x, float* __restrict__ v,
                const float* __restrict__ beta_w, const float* __restrict__ beta_b,
                const float* __restrict__ lnp_g, const float* __restrict__ lnp_b,
                float* __restrict__ pq, float* __restrict__ pk,
                float* __restrict__ betas)
{
    const int t = blockIdx.x;
    const int j = threadIdx.x;
    const size_t base = (size_t)t * DD;

    float qv = q[base + j], kv = k[base + j], xv = x[base + j];
    float eq = qv > 0.f ? qv + 1.f : expf(qv);
    float ek = kv > 0.f ? kv + 1.f : expf(kv);
    float bd = xv * beta_w[j];

    float s0 = eq, s1 = eq*eq, s2 = ek, s3 = ek*ek, s4 = bd;
    #pragma unroll
    for (int off = 32; off; off >>= 1) {
        s0 += __shfl_xor(s0, off);
        s1 += __shfl_xor(s1, off);
        s2 += __shfl_xor(s2, off);
        s3 += __shfl_xor(s3, off);
        s4 += __shfl_xor(s4, off);
    }
    __shared__ float red[4][5];
    const int lane = j & 63, w = j >> 6;
    if (lane == 0) { red[w][0]=s0; red[w][1]=s1; red[w][2]=s2; red[w][3]=s3; red[w][4]=s4; }
    __syncthreads();
    float T0 = red[0][0]+red[1][0]+red[2][0]+red[3][0];
    float T1 = red[0][1]+red[1][1]+red[2][1]+red[3][1];
    float T2 = red[0][2]+red[1][2]+red[2][2]+red[3][2];
    float T3 = red[0][3]+red[1][3]+red[2][3]+red[3][3];
    float T4 = red[0][4]+red[1][4]+red[2][4]+red[3][4];

    float mu_q = T0 * (1.f/DD);
    float var_q = T1 * (1.f/DD) - mu_q*mu_q;
    float rs_q = rsqrtf(var_q + LN_EPS);
    float mu_k = T2 * (1.f/DD);
    float var_k = T3 * (1.f/DD) - mu_k*mu_k;
    float rs_k = rsqrtf(var_k + LN_EPS);

    pq[base + j] = (eq - mu_q) * rs_q * lnp_g[j] + lnp_b[j];
    pk[base + j] = (ek - mu_k) * rs_k * lnp_g[j] + lnp_b[j];

    float beta = 1.f / (1.f + expf(-(T4 + beta_b[0])));
    v[base + j] *= beta;                 // v becomes beta*v
    if (j == 0) betas[t] = beta;
}

// ---------------------------------------------------------------------------
// band: per token t (within batch), G_m = df^{m-1} * (pk[t-m].pk[t]),
// H_m = df^{m-1} * (pk[t-m].pq[t]) for m=1..3 (0 if t-m<0).
// Layout band[g][8] = {G1,G2,G3,0, H1,H2,H3,beta}. One wave per token.
// ---------------------------------------------------------------------------
__global__ __launch_bounds__(256)
void band_kernel(const float* __restrict__ pq, const float* __restrict__ pk,
                 const float* __restrict__ betas, const float* __restrict__ decay,
                 float* __restrict__ band)
{
    const int wv = threadIdx.x >> 6, lane = threadIdx.x & 63;
    const int g = blockIdx.x * 4 + wv;       // global token 0..NT-1
    const int tt = g & (LL - 1);             // token index within batch
    const int col = lane * 4;
    const float df = 1.f / (1.f + expf(-decay[0]));

    float4 kv = *(const float4*)(pk + (size_t)g * DD + col);
    float4 qv = *(const float4*)(pq + (size_t)g * DD + col);

    float G[3], H[3];
    float dfp = 1.f;
    #pragma unroll
    for (int m = 1; m <= 3; ++m) {
        float4 km = make_float4(0.f, 0.f, 0.f, 0.f);
        if (tt >= m) km = *(const float4*)(pk + (size_t)(g - m) * DD + col);
        float gg = dot4f(km, kv), hh = dot4f(km, qv);
        gg = DPP_ADD(gg, 0x111);  hh = DPP_ADD(hh, 0x111);
        gg = DPP_ADD(gg, 0x112);  hh = DPP_ADD(hh, 0x112);
        gg = DPP_ADD(gg, 0x114);  hh = DPP_ADD(hh, 0x114);
        gg = DPP_ADD(gg, 0x118);  hh = DPP_ADD(hh, 0x118);
        gg = DPP_ADD(gg, 0x142);  hh = DPP_ADD(hh, 0x142);
        gg = DPP_ADD(gg, 0x143);  hh = DPP_ADD(hh, 0x143);
        G[m-1] = dfp * rdl63(gg);
        H[m-1] = dfp * rdl63(hh);
        dfp *= df;
    }
    if (lane == 0) {
        float4 a = make_float4(G[0], G[1], G[2], 0.f);
        float4 bvec = make_float4(H[0], H[1], H[2], betas[g]);
        *(float4*)(band + (size_t)g * 8)     = a;
        *(float4*)(band + (size_t)g * 8 + 4) = bvec;
    }
}

// ---------------------------------------------------------------------------
// Fast-weight recurrence, block-4 lookahead, 2-block-deep prefetch.
// One wave per (b,i). launch_bounds(256,1): only 1024 waves exist (1/SIMD),
// so let the allocator keep both buffer sets in VGPRs — without this the
// compiler targets 8 waves/SIMD (64 VGPR) and sinks every prefetch load to
// its use point, exposing full memory latency per block (R5/R6 lesson).
// Each STEP4 consumes set X and reloads X with data for T0+8; reloads are
// placed right after each array's last use. sched_barrier(0) pins them
// before the block boundary.
// ---------------------------------------------------------------------------
#define RED8(c) s0=DPP_ADD(s0,c); s1=DPP_ADD(s1,c); s2=DPP_ADD(s2,c); s3=DPP_ADD(s3,c); \
                p0=DPP_ADD(p0,c); p1=DPP_ADD(p1,c); p2=DPP_ADD(p2,c); p3=DPP_ADD(p3,c);

#define STEP4(T0, qq, kk, b0, b1, vv)                                           \
  {                                                                             \
    int tn = (T0) + 8; if (tn > LL - 4) tn = LL - 4;                            \
    /* dots vs block-invariant w (last use of qq) */                            \
    float s0 = dot4f(w, kk[0]),       p0 = dot4f(w, qq[0]);                     \
    float s1 = dot4f(w, kk[1]) * df,  p1 = dot4f(w, qq[1]) * df;                \
    float s2 = dot4f(w, kk[2]) * df2, p2 = dot4f(w, qq[2]) * df2;               \
    float s3 = dot4f(w, kk[3]) * df3, p3 = dot4f(w, qq[3]) * df3;               \
    /* reload qq for T0+8 */                                                    \
    _Pragma("unroll")                                                           \
    for (int pp = 0; pp < 4; ++pp)                                              \
        qq[pp] = *(const float4*)(pqb + (size_t)(tn+pp)*DD + col);              \
    /* 8 interleaved DPP reduction chains */                                    \
    RED8(0x111) RED8(0x112) RED8(0x114) RED8(0x118) RED8(0x142) RED8(0x143)     \
    const float S0 = rdl63(s0), S1 = rdl63(s1), S2 = rdl63(s2), S3 = rdl63(s3); \
    const float P0 = rdl63(p0), P1 = rdl63(p1), P2 = rdl63(p2), P3 = rdl63(p3); \
    /* scalar recursion (uses b0, b1, vv) */                                    \
    const float u0v = fmaf(-b1[0].w, S0, vv[0]);                                \
    const float rr0 = P0;                                                       \
    const float vr1 = fmaf(b0[1].x, u0v, S1);                                   \
    const float rr1 = fmaf(b1[1].x, u0v, P1);                                   \
    const float u1v = fmaf(-b1[1].w, vr1, vv[1]);                               \
    const float vr2 = fmaf(b0[2].x, u1v, fmaf(b0[2].y, u0v, S2));               \
    const float rr2 = fmaf(b1[2].x, u1v, fmaf(b1[2].y, u0v, P2));               \
    const float u2v = fmaf(-b1[2].w, vr2, vv[2]);                               \
    const float vr3 = fmaf(b0[3].x, u2v, fmaf(b0[3].y, u1v, fmaf(b0[3].z, u0v, S3))); \
    const float rr3 = fmaf(b1[3].x, u2v, fmaf(b1[3].y, u1v, fmaf(b1[3].z, u0v, P3))); \
    const float u3v = fmaf(-b1[3].w, vr3, vv[3]);                               \
    /* reload b0, b1, vv for T0+8 */                                            \
    _Pragma("unroll")                                                           \
    for (int pp = 0; pp < 4; ++pp) {                                            \
        b0[pp] = *(const float4*)(bdb + (size_t)(tn+pp)*8);                     \
        b1[pp] = *(const float4*)(bdb + (size_t)(tn+pp)*8 + 4);                 \
        vv[pp] = vbb[(size_t)(tn+pp)*DD + i];                                   \
    }                                                                           \
    /* rank-4 state update (last use of kk) */                                  \
    float4 acc;                                                                 \
    acc.x = u0v*kk[0].x; acc.y = u0v*kk[0].y; acc.z = u0v*kk[0].z; acc.w = u0v*kk[0].w; \
    acc.x = fmaf(df, acc.x, u1v*kk[1].x); acc.y = fmaf(df, acc.y, u1v*kk[1].y); \
    acc.z = fmaf(df, acc.z, u1v*kk[1].z); acc.w = fmaf(df, acc.w, u1v*kk[1].w); \
    acc.x = fmaf(df, acc.x, u2v*kk[2].x); acc.y = fmaf(df, acc.y, u2v*kk[2].y); \
    acc.z = fmaf(df, acc.z, u2v*kk[2].z); acc.w = fmaf(df, acc.w, u2v*kk[2].w); \
    acc.x = fmaf(df, acc.x, u3v*kk[3].x); acc.y = fmaf(df, acc.y, u3v*kk[3].y); \
    acc.z = fmaf(df, acc.z, u3v*kk[3].z); acc.w = fmaf(df, acc.w, u3v*kk[3].w); \
    /* reload kk for T0+8 */                                                    \
    _Pragma("unroll")                                                           \
    for (int pp = 0; pp < 4; ++pp)                                              \
        kk[pp] = *(const float4*)(pkb + (size_t)(tn+pp)*DD + col);              \
    w.x = fmaf(df4, w.x, acc.x); w.y = fmaf(df4, w.y, acc.y);                   \
    w.z = fmaf(df4, w.z, acc.z); w.w = fmaf(df4, w.w, acc.w);                   \
    if (lane == 0) {                                                            \
        yb[(size_t)((T0)+0)*DD + i] = rr0;                                      \
        yb[(size_t)((T0)+1)*DD + i] = rr1;                                      \
        yb[(size_t)((T0)+2)*DD + i] = rr2;                                      \
        yb[(size_t)((T0)+3)*DD + i] = rr3;                                      \
    }                                                                           \
    __builtin_amdgcn_sched_barrier(0);                                          \
  }

__global__ __launch_bounds__(256, 1)
void recur_kernel(const float* __restrict__ pq, const float* __restrict__ pk,
                  const float* __restrict__ vbeta, const float* __restrict__ band,
                  const float* __restrict__ decay, float* __restrict__ y)
{
    // XCD swizzle (bijective on 0..255)
    const int xcd  = blockIdx.x & 7;
    const int slot = blockIdx.x >> 3;
    const int vblk = xcd * 32 + slot;

    const int gtid = vblk * 256 + threadIdx.x;
    const int wid  = gtid >> 6;
    const int lane = threadIdx.x & 63;
    const int b = wid >> 8;
    const int i = wid & 255;

    const float df  = 1.f / (1.f + expf(-decay[0]));
    const float df2 = df * df, df3 = df2 * df, df4 = df2 * df2;

    const float* pqb = pq    + (size_t)b * LL * DD;
    const float* pkb = pk    + (size_t)b * LL * DD;
    const float* vbb = vbeta + (size_t)b * LL * DD;
    const float* bdb = band  + (size_t)b * LL * 8;
    float* yb = y + (size_t)b * LL * DD;
    const int col = lane * 4;

    float4 w = make_float4(0.f, 0.f, 0.f, 0.f);

    float4 qA[4], kA[4], bA0[4], bA1[4]; float vA[4];
    float4 qB[4], kB[4], bB0[4], bB1[4]; float vB[4];

    #pragma unroll
    for (int p = 0; p < 4; ++p) {
        qA[p]  = *(const float4*)(pqb + (size_t)p * DD + col);
        kA[p]  = *(const float4*)(pkb + (size_t)p * DD + col);
        bA0[p] = *(const float4*)(bdb + (size_t)p * 8);
        bA1[p] = *(const float4*)(bdb + (size_t)p * 8 + 4);
        vA[p]  = vbb[(size_t)p * DD + i];
    }
    #pragma unroll
    for (int p = 0; p < 4; ++p) {
        qB[p]  = *(const float4*)(pqb + (size_t)(4+p) * DD + col);
        kB[p]  = *(const float4*)(pkb + (size_t)(4+p) * DD + col);
        bB0[p] = *(const float4*)(bdb + (size_t)(4+p) * 8);
        bB1[p] = *(const float4*)(bdb + (size_t)(4+p) * 8 + 4);
        vB[p]  = vbb[(size_t)(4+p) * DD + i];
    }

    for (int t0 = 0; t0 < LL; t0 += 8) {
        STEP4(t0,     qA, kA, bA0, bA1, vA)
        STEP4(t0 + 4, qB, kB, bB0, bB1, vB)
    }
}

// ---------------------------------------------------------------------------
// LN kernel: per token LN(y) with ln_g, ln_b
// ---------------------------------------------------------------------------
__global__ __launch_bounds__(256)
void ln_kernel(const float* __restrict__ y, const float* __restrict__ g,
               const float* __restrict__ b, float* __restrict__ out)
{
    const int t = blockIdx.x;
    const int j = threadIdx.x;
    const size_t base = (size_t)t * DD;
    float v = y[base + j];
    float s0 = v, s1 = v*v;
    #pragma unroll
    for (int off = 32; off; off >>= 1) {
        s0 += __shfl_xor(s0, off);
        s1 += __shfl_xor(s1, off);
    }
    __shared__ float red[4][2];
    const int lane = j & 63, w = j >> 6;
    if (lane == 0) { red[w][0]=s0; red[w][1]=s1; }
    __syncthreads();
    float T0 = red[0][0]+red[1][0]+red[2][0]+red[3][0];
    float T1 = red[0][1]+red[1][1]+red[2][1]+red[3][1];
    float mu = T0 * (1.f/DD);
    float var = T1 * (1.f/DD) - mu*mu;
    float rs = rsqrtf(var + LN_EPS);
    out[base + j] = (v - mu) * rs * g[j] + b[j];
}

// ---------------------------------------------------------------------------
extern "C" void kernel_launch(void* const* d_in, const int* in_sizes, int n_in,
                              void* d_out, int out_size, void* d_ws, size_t ws_size,
                              hipStream_t stream)
{
    const float* x      = (const float*)d_in[0];
    const float* Wq     = (const float*)d_in[1];
    const float* Wk     = (const float*)d_in[2];
    const float* Wv     = (const float*)d_in[3];
    const float* beta_w = (const float*)d_in[4];
    const float* beta_b = (const float*)d_in[5];
    const float* decay  = (const float*)d_in[6];
    const float* Wo     = (const float*)d_in[7];
    const float* bo     = (const float*)d_in[8];
    const float* ln_g   = (const float*)d_in[9];
    const float* ln_b   = (const float*)d_in[10];
    const float* lnp_g  = (const float*)d_in[11];
    const float* lnp_b  = (const float*)d_in[12];

    float* ws = (float*)d_ws;
    float* q_st  = ws + OFF_Y;
    float* k_st  = ws + OFF_LNY;
    float* v_st  = ws + OFF_V;     // scaled to beta*v by phi
    float* pq    = ws + OFF_PQ;
    float* pk    = ws + OFF_PK;
    float* betas = ws + OFF_BETA;
    float* band  = ws + OFF_BAND;

    // fused q/k/v projections
    gemm_qkv_kernel<<<dim3(NT/64, DD/64, 3), 256, 0, stream>>>(
        x, Wq, Wk, Wv, q_st, k_st, v_st);

    // phi + beta (+ v *= beta in place)
    phi_kernel<<<NT, 256, 0, stream>>>(q_st, k_st, x, v_st, beta_w, beta_b,
                                       lnp_g, lnp_b, pq, pk, betas);

    // Gram band (fully parallel)
    band_kernel<<<NT/4, 256, 0, stream>>>(pq, pk, betas, decay, band);

    // sequential fast-weight recurrence (block-4 lookahead, 2-block prefetch)
    recur_kernel<<<256, 256, 0, stream>>>(pq, pk, v_st, band, decay, ws + OFF_Y);

    // final LN + output projection
    ln_kernel<<<NT, 256, 0, stream>>>(ws + OFF_Y, ln_g, ln_b, ws + OFF_LNY);
    gemm_nt_kernel<<<dim3(NT/64, DD/64), 256, 0, stream>>>(ws + OFF_LNY, Wo, bo, (float*)d_out);
}

// Round 9
// 217.219 us; speedup vs baseline: 2.1957x; 1.0790x over previous
//
#include <hip/hip_runtime.h>
#include <math.h>

#define BB 4
#define LL 1024
#define DD 256
#define NT (BB*LL)          // 4096 tokens
#define LN_EPS 1e-5f

// workspace layout (floats)
#define OFF_PQ   0
#define OFF_PK   (NT*DD)
#define OFF_V    (2*NT*DD)      // becomes beta*v after phi (in-place)
#define OFF_Y    (3*NT*DD)      // also q staging before phi
#define OFF_LNY  (4*NT*DD)      // also k staging before phi
#define OFF_BETA (5*NT*DD)
#define OFF_BAND (5*NT*DD + NT) // NT*8 floats: {G1,G2,G3,0, H1,H2,H3,beta}

// Builtin DPP add (compiler inserts DPP hazard nops): x + dpp_move(x,ctrl),
// invalid lanes contribute 0 (bound_ctrl=true). row_shr 1/2/4/8 accumulate
// row sums into lanes 15/31/47/63; row_bcast15/31 cascade; total in lane 63.
#define DPP_ADD(x, ctrl) ((x) + __uint_as_float(__builtin_amdgcn_update_dpp( \
        0u, __float_as_uint(x), (ctrl), 0xf, 0xf, true)))
#define DPP_RED6(x) x = DPP_ADD(x, 0x111); x = DPP_ADD(x, 0x112); \
                    x = DPP_ADD(x, 0x114); x = DPP_ADD(x, 0x118); \
                    x = DPP_ADD(x, 0x142); x = DPP_ADD(x, 0x143);

__device__ __forceinline__ float dot4f(float4 a, float4 b) {
    return fmaf(a.x, b.x, a.y * b.y) + fmaf(a.z, b.z, a.w * b.w);
}
__device__ __forceinline__ float rdl63(float x) {
    return __uint_as_float((unsigned)__builtin_amdgcn_readlane(__float_as_uint(x), 63));
}

// ---------------------------------------------------------------------------
// GEMM core: C[t][j] = sum_d A[t][d] * W[j][d] (+bias). BM=64,BN=64,BK=16.
// ---------------------------------------------------------------------------
__device__ __forceinline__
void gemm_body(const float* __restrict__ A, const float* __restrict__ W,
               const float* __restrict__ bias, float* __restrict__ C,
               int t0, int j0)
{
    __shared__ float As[64][17];
    __shared__ float Bs[64][17];
    const int tid = threadIdx.x;
    const int ty = tid >> 4, tx = tid & 15;
    const int lr = tid >> 2, lc = (tid & 3) << 2;

    float acc[4][4];
    #pragma unroll
    for (int m = 0; m < 4; ++m)
        #pragma unroll
        for (int n = 0; n < 4; ++n) acc[m][n] = 0.f;

    for (int d0 = 0; d0 < DD; d0 += 16) {
        float4 av = *(const float4*)(A + (size_t)(t0 + lr) * DD + d0 + lc);
        float4 bv = *(const float4*)(W + (size_t)(j0 + lr) * DD + d0 + lc);
        As[lr][lc] = av.x; As[lr][lc+1] = av.y; As[lr][lc+2] = av.z; As[lr][lc+3] = av.w;
        Bs[lr][lc] = bv.x; Bs[lr][lc+1] = bv.y; Bs[lr][lc+2] = bv.z; Bs[lr][lc+3] = bv.w;
        __syncthreads();
        #pragma unroll
        for (int kk = 0; kk < 16; ++kk) {
            float a[4], b[4];
            #pragma unroll
            for (int m = 0; m < 4; ++m) a[m] = As[ty*4+m][kk];
            #pragma unroll
            for (int n = 0; n < 4; ++n) b[n] = Bs[tx*4+n][kk];
            #pragma unroll
            for (int m = 0; m < 4; ++m)
                #pragma unroll
                for (int n = 0; n < 4; ++n) acc[m][n] += a[m]*b[n];
        }
        __syncthreads();
    }

    #pragma unroll
    for (int m = 0; m < 4; ++m) {
        float4 o;
        o.x = acc[m][0]; o.y = acc[m][1]; o.z = acc[m][2]; o.w = acc[m][3];
        if (bias) {
            o.x += bias[j0 + tx*4 + 0];
            o.y += bias[j0 + tx*4 + 1];
            o.z += bias[j0 + tx*4 + 2];
            o.w += bias[j0 + tx*4 + 3];
        }
        *(float4*)(C + (size_t)(t0 + ty*4 + m) * DD + j0 + tx*4) = o;
    }
}

__global__ __launch_bounds__(256)
void gemm_qkv_kernel(const float* __restrict__ x,
                     const float* __restrict__ Wq, const float* __restrict__ Wk,
                     const float* __restrict__ Wv,
                     float* __restrict__ q, float* __restrict__ k, float* __restrict__ v)
{
    const float* W = (blockIdx.z == 0) ? Wq : (blockIdx.z == 1) ? Wk : Wv;
    float*       C = (blockIdx.z == 0) ? q  : (blockIdx.z == 1) ? k  : v;
    gemm_body(x, W, nullptr, C, blockIdx.x * 64, blockIdx.y * 64);
}

__global__ __launch_bounds__(256)
void gemm_nt_kernel(const float* __restrict__ A, const float* __restrict__ W,
                    const float* __restrict__ bias, float* __restrict__ C)
{
    gemm_body(A, W, bias, C, blockIdx.x * 64, blockIdx.y * 64);
}

// ---------------------------------------------------------------------------
// phi: wave-per-token (64 lanes x float4). pq = LN(elu(q)+1), pk = LN(elu(k)+1),
// beta = sigmoid(x.bw + bb), v *= beta. No LDS, no block sync.
// ---------------------------------------------------------------------------
__global__ __launch_bounds__(256)
void phi_kernel(const float* __restrict__ q, const float* __restrict__ k,
                const float* __restrict__ x, float* __restrict__ v,
                const float* __restrict__ beta_w, const float* __restrict__ beta_b,
                const float* __restrict__ lnp_g, const float* __restrict__ lnp_b,
                float* __restrict__ pq, float* __restrict__ pk,
                float* __restrict__ betas)
{
    const int t = blockIdx.x * 4 + (threadIdx.x >> 6);
    const int lane = threadIdx.x & 63;
    const int col = lane * 4;
    const size_t base = (size_t)t * DD + col;

    float4 q4 = *(const float4*)(q + base);
    float4 k4 = *(const float4*)(k + base);
    float4 x4 = *(const float4*)(x + base);
    float4 bw4 = *(const float4*)(beta_w + col);

    float4 eq, ek;
    eq.x = q4.x > 0.f ? q4.x + 1.f : expf(q4.x);
    eq.y = q4.y > 0.f ? q4.y + 1.f : expf(q4.y);
    eq.z = q4.z > 0.f ? q4.z + 1.f : expf(q4.z);
    eq.w = q4.w > 0.f ? q4.w + 1.f : expf(q4.w);
    ek.x = k4.x > 0.f ? k4.x + 1.f : expf(k4.x);
    ek.y = k4.y > 0.f ? k4.y + 1.f : expf(k4.y);
    ek.z = k4.z > 0.f ? k4.z + 1.f : expf(k4.z);
    ek.w = k4.w > 0.f ? k4.w + 1.f : expf(k4.w);

    float s0 = eq.x + eq.y + eq.z + eq.w;
    float s1 = dot4f(eq, eq);
    float s2 = ek.x + ek.y + ek.z + ek.w;
    float s3 = dot4f(ek, ek);
    float s4 = dot4f(x4, bw4);

    DPP_RED6(s0) DPP_RED6(s1) DPP_RED6(s2) DPP_RED6(s3) DPP_RED6(s4)
    float T0 = rdl63(s0), T1 = rdl63(s1), T2 = rdl63(s2), T3 = rdl63(s3), T4 = rdl63(s4);

    float mu_q = T0 * (1.f/DD);
    float rs_q = rsqrtf(T1 * (1.f/DD) - mu_q*mu_q + LN_EPS);
    float mu_k = T2 * (1.f/DD);
    float rs_k = rsqrtf(T3 * (1.f/DD) - mu_k*mu_k + LN_EPS);
    float beta = 1.f / (1.f + expf(-(T4 + beta_b[0])));

    float4 g4 = *(const float4*)(lnp_g + col);
    float4 b4 = *(const float4*)(lnp_b + col);
    float4 oq, ok;
    oq.x = (eq.x - mu_q) * rs_q * g4.x + b4.x;
    oq.y = (eq.y - mu_q) * rs_q * g4.y + b4.y;
    oq.z = (eq.z - mu_q) * rs_q * g4.z + b4.z;
    oq.w = (eq.w - mu_q) * rs_q * g4.w + b4.w;
    ok.x = (ek.x - mu_k) * rs_k * g4.x + b4.x;
    ok.y = (ek.y - mu_k) * rs_k * g4.y + b4.y;
    ok.z = (ek.z - mu_k) * rs_k * g4.z + b4.z;
    ok.w = (ek.w - mu_k) * rs_k * g4.w + b4.w;
    *(float4*)(pq + base) = oq;
    *(float4*)(pk + base) = ok;

    float4 v4 = *(const float4*)(v + base);
    v4.x *= beta; v4.y *= beta; v4.z *= beta; v4.w *= beta;
    *(float4*)(v + base) = v4;
    if (lane == 0) betas[t] = beta;
}

// ---------------------------------------------------------------------------
// band: per token t, G_m = df^{m-1}*(pk[t-m].pk[t]), H_m = df^{m-1}*(pk[t-m].pq[t]),
// m=1..3. band[g][8] = {G1,G2,G3,0, H1,H2,H3,beta}. One wave per token.
// ---------------------------------------------------------------------------
__global__ __launch_bounds__(256)
void band_kernel(const float* __restrict__ pq, const float* __restrict__ pk,
                 const float* __restrict__ betas, const float* __restrict__ decay,
                 float* __restrict__ band)
{
    const int wv = threadIdx.x >> 6, lane = threadIdx.x & 63;
    const int g = blockIdx.x * 4 + wv;       // global token 0..NT-1
    const int tt = g & (LL - 1);             // token index within batch
    const int col = lane * 4;
    const float df = 1.f / (1.f + expf(-decay[0]));

    float4 kv = *(const float4*)(pk + (size_t)g * DD + col);
    float4 qv = *(const float4*)(pq + (size_t)g * DD + col);

    float gg1 = 0.f, hh1 = 0.f, gg2 = 0.f, hh2 = 0.f, gg3 = 0.f, hh3 = 0.f;
    if (tt >= 1) { float4 km = *(const float4*)(pk + (size_t)(g-1) * DD + col);
                   gg1 = dot4f(km, kv); hh1 = dot4f(km, qv); }
    if (tt >= 2) { float4 km = *(const float4*)(pk + (size_t)(g-2) * DD + col);
                   gg2 = dot4f(km, kv); hh2 = dot4f(km, qv); }
    if (tt >= 3) { float4 km = *(const float4*)(pk + (size_t)(g-3) * DD + col);
                   gg3 = dot4f(km, kv); hh3 = dot4f(km, qv); }

    DPP_RED6(gg1) DPP_RED6(hh1) DPP_RED6(gg2) DPP_RED6(hh2) DPP_RED6(gg3) DPP_RED6(hh3)

    if (lane == 63) {
        float4 a = make_float4(gg1, df*gg2, df*df*gg3, 0.f);
        float4 bvec = make_float4(hh1, df*hh2, df*df*hh3, betas[g]);
        *(float4*)(band + (size_t)g * 8)     = a;
        *(float4*)(band + (size_t)g * 8 + 4) = bvec;
    }
}

// ---------------------------------------------------------------------------
// Fast-weight recurrence, block-4 lookahead, 2-block prefetch.
// Butterfly rounds are single asm blocks of 8 interleaved single-inst DPP
// adds: within a block all 8 chains are independent; dependent ops across
// rounds sit 8 instructions apart (>= the required 2 DPP wait states), so
// the hazard is satisfied by construction. s_nop 1 guards block entry
// (producer FMA may be adjacent) and exit (readlane/FMA consumers).
// Recursion runs IN-LANE on lane-63-valid values (v/band are wave-uniform);
// u0..u3 broadcast post-chain; rr stored from lane 63.
// ---------------------------------------------------------------------------
#define RED_ROUND(mod, pre)                                                     \
    asm(pre                                                                     \
        "v_add_f32 %0, %0, %0 " mod " bound_ctrl:0\n\t"                         \
        "v_add_f32 %1, %1, %1 " mod " bound_ctrl:0\n\t"                         \
        "v_add_f32 %2, %2, %2 " mod " bound_ctrl:0\n\t"                         \
        "v_add_f32 %3, %3, %3 " mod " bound_ctrl:0\n\t"                         \
        "v_add_f32 %4, %4, %4 " mod " bound_ctrl:0\n\t"                         \
        "v_add_f32 %5, %5, %5 " mod " bound_ctrl:0\n\t"                         \
        "v_add_f32 %6, %6, %6 " mod " bound_ctrl:0\n\t"                         \
        "v_add_f32 %7, %7, %7 " mod " bound_ctrl:0"                             \
        : "+v"(s0), "+v"(s1), "+v"(s2), "+v"(s3),                               \
          "+v"(p0), "+v"(p1), "+v"(p2), "+v"(p3));

#define STEP4(T0, qq, kk, b0, b1, vv)                                           \
  {                                                                             \
    int tn = (T0) + 8; if (tn > LL - 4) tn = LL - 4;                            \
    float s0 = dot4f(w, kk[0]),       p0 = dot4f(w, qq[0]);                     \
    float s1 = dot4f(w, kk[1]) * df,  p1 = dot4f(w, qq[1]) * df;                \
    float s2 = dot4f(w, kk[2]) * df2, p2 = dot4f(w, qq[2]) * df2;               \
    float s3 = dot4f(w, kk[3]) * df3, p3 = dot4f(w, qq[3]) * df3;               \
    _Pragma("unroll")                                                           \
    for (int pp = 0; pp < 4; ++pp)                                              \
        qq[pp] = *(const float4*)(pqb + (size_t)(tn+pp)*DD + col);              \
    RED_ROUND("row_shr:1",   "s_nop 1\n\t")                                     \
    RED_ROUND("row_shr:2",   "")                                                \
    RED_ROUND("row_shr:4",   "")                                                \
    RED_ROUND("row_shr:8",   "")                                                \
    RED_ROUND("row_bcast:15","")                                                \
    RED_ROUND("row_bcast:31","")                                                \
    asm volatile("s_nop 1");                                                    \
    /* in-lane recursion: valid in lane 63 (vv/b are wave-uniform) */           \
    const float u0v = fmaf(-b1[0].w, s0, vv[0]);                                \
    const float rr0 = p0;                                                       \
    const float vr1 = fmaf(b0[1].x, u0v, s1);                                   \
    const float rr1 = fmaf(b1[1].x, u0v, p1);                                   \
    const float u1v = fmaf(-b1[1].w, vr1, vv[1]);                               \
    const float vr2 = fmaf(b0[2].x, u1v, fmaf(b0[2].y, u0v, s2));               \
    const float rr2 = fmaf(b1[2].x, u1v, fmaf(b1[2].y, u0v, p2));               \
    const float u2v = fmaf(-b1[2].w, vr2, vv[2]);                               \
    const float vr3 = fmaf(b0[3].x, u2v, fmaf(b0[3].y, u1v, fmaf(b0[3].z, u0v, s3))); \
    const float rr3 = fmaf(b1[3].x, u2v, fmaf(b1[3].y, u1v, fmaf(b1[3].z, u0v, p3))); \
    const float u3v = fmaf(-b1[3].w, vr3, vv[3]);                               \
    _Pragma("unroll")                                                           \
    for (int pp = 0; pp < 4; ++pp) {                                            \
        b0[pp] = *(const float4*)(bdb + (size_t)(tn+pp)*8);                     \
        b1[pp] = *(const float4*)(bdb + (size_t)(tn+pp)*8 + 4);                 \
        vv[pp] = vbb[(size_t)(tn+pp)*DD + i];                                   \
    }                                                                           \
    /* broadcast the four u's (post-recursion, off the S-chain) */              \
    const float u0 = rdl63(u0v), u1 = rdl63(u1v), u2 = rdl63(u2v), u3 = rdl63(u3v); \
    float4 acc;                                                                 \
    acc.x = u0*kk[0].x; acc.y = u0*kk[0].y; acc.z = u0*kk[0].z; acc.w = u0*kk[0].w; \
    acc.x = fmaf(df, acc.x, u1*kk[1].x); acc.y = fmaf(df, acc.y, u1*kk[1].y);   \
    acc.z = fmaf(df, acc.z, u1*kk[1].z); acc.w = fmaf(df, acc.w, u1*kk[1].w);   \
    acc.x = fmaf(df, acc.x, u2*kk[2].x); acc.y = fmaf(df, acc.y, u2*kk[2].y);   \
    acc.z = fmaf(df, acc.z, u2*kk[2].z); acc.w = fmaf(df, acc.w, u2*kk[2].w);   \
    acc.x = fmaf(df, acc.x, u3*kk[3].x); acc.y = fmaf(df, acc.y, u3*kk[3].y);   \
    acc.z = fmaf(df, acc.z, u3*kk[3].z); acc.w = fmaf(df, acc.w, u3*kk[3].w);   \
    _Pragma("unroll")                                                           \
    for (int pp = 0; pp < 4; ++pp)                                              \
        kk[pp] = *(const float4*)(pkb + (size_t)(tn+pp)*DD + col);              \
    w.x = fmaf(df4, w.x, acc.x); w.y = fmaf(df4, w.y, acc.y);                   \
    w.z = fmaf(df4, w.z, acc.z); w.w = fmaf(df4, w.w, acc.w);                   \
    if (lane == 63) {                                                           \
        yb[(size_t)((T0)+0)*DD + i] = rr0;                                      \
        yb[(size_t)((T0)+1)*DD + i] = rr1;                                      \
        yb[(size_t)((T0)+2)*DD + i] = rr2;                                      \
        yb[(size_t)((T0)+3)*DD + i] = rr3;                                      \
    }                                                                           \
    __builtin_amdgcn_sched_barrier(0);                                          \
  }

__global__ __launch_bounds__(256, 1)
void recur_kernel(const float* __restrict__ pq, const float* __restrict__ pk,
                  const float* __restrict__ vbeta, const float* __restrict__ band,
                  const float* __restrict__ decay, float* __restrict__ y)
{
    // XCD swizzle (bijective on 0..255)
    const int xcd  = blockIdx.x & 7;
    const int slot = blockIdx.x >> 3;
    const int vblk = xcd * 32 + slot;

    const int gtid = vblk * 256 + threadIdx.x;
    const int wid  = gtid >> 6;
    const int lane = threadIdx.x & 63;
    const int b = wid >> 8;
    const int i = wid & 255;

    const float df  = 1.f / (1.f + expf(-decay[0]));
    const float df2 = df * df, df3 = df2 * df, df4 = df2 * df2;

    const float* pqb = pq    + (size_t)b * LL * DD;
    const float* pkb = pk    + (size_t)b * LL * DD;
    const float* vbb = vbeta + (size_t)b * LL * DD;
    const float* bdb = band  + (size_t)b * LL * 8;
    float* yb = y + (size_t)b * LL * DD;
    const int col = lane * 4;

    float4 w = make_float4(0.f, 0.f, 0.f, 0.f);

    float4 qA[4], kA[4], bA0[4], bA1[4]; float vA[4];
    float4 qB[4], kB[4], bB0[4], bB1[4]; float vB[4];

    #pragma unroll
    for (int p = 0; p < 4; ++p) {
        qA[p]  = *(const float4*)(pqb + (size_t)p * DD + col);
        kA[p]  = *(const float4*)(pkb + (size_t)p * DD + col);
        bA0[p] = *(const float4*)(bdb + (size_t)p * 8);
        bA1[p] = *(const float4*)(bdb + (size_t)p * 8 + 4);
        vA[p]  = vbb[(size_t)p * DD + i];
    }
    #pragma unroll
    for (int p = 0; p < 4; ++p) {
        qB[p]  = *(const float4*)(pqb + (size_t)(4+p) * DD + col);
        kB[p]  = *(const float4*)(pkb + (size_t)(4+p) * DD + col);
        bB0[p] = *(const float4*)(bdb + (size_t)(4+p) * 8);
        bB1[p] = *(const float4*)(bdb + (size_t)(4+p) * 8 + 4);
        vB[p]  = vbb[(size_t)(4+p) * DD + i];
    }

    for (int t0 = 0; t0 < LL; t0 += 8) {
        STEP4(t0,     qA, kA, bA0, bA1, vA)
        STEP4(t0 + 4, qB, kB, bB0, bB1, vB)
    }
}

// ---------------------------------------------------------------------------
// LN: wave-per-token (float4 lanes), DPP reduce, no LDS/sync.
// ---------------------------------------------------------------------------
__global__ __launch_bounds__(256)
void ln_kernel(const float* __restrict__ y, const float* __restrict__ g,
               const float* __restrict__ b, float* __restrict__ out)
{
    const int t = blockIdx.x * 4 + (threadIdx.x >> 6);
    const int lane = threadIdx.x & 63;
    const int col = lane * 4;
    const size_t base = (size_t)t * DD + col;

    float4 v4 = *(const float4*)(y + base);
    float s0 = v4.x + v4.y + v4.z + v4.w;
    float s1 = dot4f(v4, v4);
    DPP_RED6(s0) DPP_RED6(s1)
    float T0 = rdl63(s0), T1 = rdl63(s1);
    float mu = T0 * (1.f/DD);
    float rs = rsqrtf(T1 * (1.f/DD) - mu*mu + LN_EPS);

    float4 g4 = *(const float4*)(g + col);
    float4 b4 = *(const float4*)(b + col);
    float4 o;
    o.x = (v4.x - mu) * rs * g4.x + b4.x;
    o.y = (v4.y - mu) * rs * g4.y + b4.y;
    o.z = (v4.z - mu) * rs * g4.z + b4.z;
    o.w = (v4.w - mu) * rs * g4.w + b4.w;
    *(float4*)(out + base) = o;
}

// ---------------------------------------------------------------------------
extern "C" void kernel_launch(void* const* d_in, const int* in_sizes, int n_in,
                              void* d_out, int out_size, void* d_ws, size_t ws_size,
                              hipStream_t stream)
{
    const float* x      = (const float*)d_in[0];
    const float* Wq     = (const float*)d_in[1];
    const float* Wk     = (const float*)d_in[2];
    const float* Wv     = (const float*)d_in[3];
    const float* beta_w = (const float*)d_in[4];
    const float* beta_b = (const float*)d_in[5];
    const float* decay  = (const float*)d_in[6];
    const float* Wo     = (const float*)d_in[7];
    const float* bo     = (const float*)d_in[8];
    const float* ln_g   = (const float*)d_in[9];
    const float* ln_b   = (const float*)d_in[10];
    const float* lnp_g  = (const float*)d_in[11];
    const float* lnp_b  = (const float*)d_in[12];

    float* ws = (float*)d_ws;
    float* q_st  = ws + OFF_Y;
    float* k_st  = ws + OFF_LNY;
    float* v_st  = ws + OFF_V;     // scaled to beta*v by phi
    float* pq    = ws + OFF_PQ;
    float* pk    = ws + OFF_PK;
    float* betas = ws + OFF_BETA;
    float* band  = ws + OFF_BAND;

    // fused q/k/v projections
    gemm_qkv_kernel<<<dim3(NT/64, DD/64, 3), 256, 0, stream>>>(
        x, Wq, Wk, Wv, q_st, k_st, v_st);

    // phi + beta (+ v *= beta in place)
    phi_kernel<<<NT/4, 256, 0, stream>>>(q_st, k_st, x, v_st, beta_w, beta_b,
                                         lnp_g, lnp_b, pq, pk, betas);

    // Gram band (fully parallel)
    band_kernel<<<NT/4, 256, 0, stream>>>(pq, pk, betas, decay, band);

    // sequential fast-weight recurrence
    recur_kernel<<<256, 256, 0, stream>>>(pq, pk, v_st, band, decay, ws + OFF_Y);

    // final LN + output projection
    ln_kernel<<<NT/4, 256, 0, stream>>>(ws + OFF_Y, ln_g, ln_b, ws + OFF_LNY);
    gemm_nt_kernel<<<dim3(NT/64, DD/64), 256, 0, stream>>>(ws + OFF_LNY, Wo, bo, (float*)d_out);
}